// Round 7
// baseline (177.252 us; speedup 1.0000x reference)
//
#include <hip/hip_runtime.h>
#include <hip/hip_bf16.h>
#include <math.h>

#define B 8
#define C 256
#define HEADS 8
#define D 32
#define NPIX 1024
#define OC 768
#define SCALE 0.17677669529663687f   // 1/sqrt(32)
#define LOG2E 1.4426950408889634f

typedef unsigned int uint;
typedef unsigned short u16;
typedef __attribute__((ext_vector_type(8))) short bf16x8;
typedef __attribute__((ext_vector_type(4))) short bf16x4;
typedef __attribute__((ext_vector_type(4))) float f32x4;

static __device__ inline u16 f2bf(float f) {   // RNE f32->bf16
  uint u = __float_as_uint(f);
  return (u16)((u + 0x7fffu + ((u >> 16) & 1u)) >> 16);
}
static __device__ inline float bf_lo(uint u) { return __uint_as_float(u << 16); }
static __device__ inline float bf_hi(uint u) { return __uint_as_float(u & 0xffff0000u); }

// packed f32x2 -> bf16x2 (lowers to v_cvt_pk_bf16_f32 on gfx950)
static __device__ inline uint pk2(float lo, float hi) {
  union { __hip_bfloat162 h; uint u; } cv;
  cv.h = __float22bfloat162_rn(float2{lo, hi});
  return cv.u;
}

// ---------------------------------------------------------------------------
// P0: fused prep. Blocks [0,256): weights fp32->bf16 (wqkv then wout).
// Blocks [256,768): transpose-convert x[b][c][pix] -> XT[b][pix][c] bf16.
// ---------------------------------------------------------------------------
__global__ __launch_bounds__(256) void k_prep(
    const float* __restrict__ x, const float* __restrict__ wqkv,
    const float* __restrict__ wout,
    u16* __restrict__ WQ, u16* __restrict__ WO, u16* __restrict__ XT) {
  const int bid = blockIdx.x, t = threadIdx.x;
  __shared__ u16 tile[64][65];
  if (bid < 256) {
    const float* src;
    u16* dst;
    int base;
    if (bid < 192) { src = wqkv; dst = WQ; base = bid * 1024; }
    else           { src = wout; dst = WO; base = (bid - 192) * 1024; }
    float4 v = *(const float4*)(src + base + t * 4);
    uint2 pk = make_uint2((uint)f2bf(v.x) | ((uint)f2bf(v.y) << 16),
                          (uint)f2bf(v.z) | ((uint)f2bf(v.w) << 16));
    *(uint2*)(dst + base + t * 4) = pk;
    return;
  }
  const int id = bid - 256;
  const int pt = id & 15, ct = (id >> 4) & 3, b = id >> 6;
  {
    const int px = t & 63, cq = t >> 6;
    const float* xb = x + ((size_t)(b * C + ct * 64)) * NPIX + pt * 64;
#pragma unroll
    for (int m = 0; m < 16; ++m) {
      const int c = cq * 16 + m;
      tile[c][px] = f2bf(xb[(size_t)c * NPIX + px]);
    }
  }
  __syncthreads();
  {
    const int cc = t & 63, pq = t >> 6;
    u16* dst = XT + ((size_t)(b * NPIX + pt * 64)) * C + ct * 64;
#pragma unroll
    for (int m = 0; m < 16; ++m) {
      const int pix = pq * 16 + m;
      dst[(size_t)pix * C + cc] = tile[cc][pix];
    }
  }
}

// ---------------------------------------------------------------------------
// K1: QKV GEMM via MFMA. D[o][pix] = W[o][c] . XT[pix][c]^T.
// Q pre-scaled by SCALE*LOG2E (k_red diag compensates).
// V stored in FRAGMENT-ORDER layout VF so k_attn's PV B-fragment loads are
// fully coalesced 8B/lane bursts:
//   VF[bh][ ((jb16*2 + nt)*64 + quad*16 + l15)*4 + m ]
//     = V[j = jb16*16 + quad*4 + m][d = nt*16 + l15]
// ---------------------------------------------------------------------------
__global__ __launch_bounds__(256) void k_qkv_mfma(
    const u16* __restrict__ XT, const u16* __restrict__ WQ,
    u16* __restrict__ Q, u16* __restrict__ Kk, u16* __restrict__ VT) {
  const int ob = blockIdx.x, pb = blockIdx.y, b = blockIdx.z;
  const int wv = threadIdx.x >> 6, lane = threadIdx.x & 63;
  const int quad = lane >> 4, l15 = lane & 15;
  const int part = ob >> 2;
  const int odl = (ob & 3) * 64 + wv * 16;
  const int hh = odl >> 5, d0 = odl & 31;
  const int bh = b * HEADS + hh;
  const int pix0 = pb * 128;

  const u16* arow = WQ + (size_t)(ob * 64 + wv * 16 + l15) * C;
  bf16x8 af[8];
#pragma unroll
  for (int kc = 0; kc < 8; ++kc)
    af[kc] = *(const bf16x8*)(arow + kc * 32 + quad * 8);

  const u16* xb = XT + (size_t)(b * NPIX + pix0) * C;
  f32x4 acc[8];
#pragma unroll
  for (int nt = 0; nt < 8; ++nt) acc[nt] = (f32x4){0.f, 0.f, 0.f, 0.f};

  for (int kc = 0; kc < 8; ++kc) {
#pragma unroll
    for (int nt = 0; nt < 8; ++nt) {
      bf16x8 bfr = *(const bf16x8*)(xb + (size_t)(nt * 16 + l15) * C +
                                    kc * 32 + quad * 8);
      acc[nt] = __builtin_amdgcn_mfma_f32_16x16x32_bf16(af[kc], bfr, acc[nt], 0, 0, 0);
    }
  }

  if (part < 2) {
    const float qs = (part == 0) ? (SCALE * LOG2E) : 1.f;
    u16* dst = (part == 0 ? Q : Kk) + (size_t)bh * NPIX * D;
#pragma unroll
    for (int nt = 0; nt < 8; ++nt) {
      const int pix = pix0 + nt * 16 + l15;
      uint2 pk = make_uint2(
          (uint)f2bf(acc[nt][0] * qs) | ((uint)f2bf(acc[nt][1] * qs) << 16),
          (uint)f2bf(acc[nt][2] * qs) | ((uint)f2bf(acc[nt][3] * qs) << 16));
      *(uint2*)(dst + (size_t)pix * D + d0 + 4 * quad) = pk;
    }
  } else {
    u16* vb = VT + (size_t)bh * NPIX * D;
#pragma unroll
    for (int nt = 0; nt < 8; ++nt) {
      const int pix = pix0 + nt * 16 + l15;           // j
      const int jb16 = pix >> 4, qa = (pix >> 2) & 3, m = pix & 3;
#pragma unroll
      for (int r = 0; r < 4; ++r) {
        const int d = d0 + 4 * quad + r;              // 0..31
        const int nta = d >> 4, l15a = d & 15;
        vb[((size_t)(jb16 * 2 + nta) * 64 + qa * 16 + l15a) * 4 + m] =
            f2bf(acc[nt][r]);
      }
    }
  }
}

// ---------------------------------------------------------------------------
// R: fused reductions. Blocks [0,8): diag_vec[b] (Q carries SCALE*LOG2E, so
// final factor is 0.125/LOG2E). Blocks [8,72): colsum[bh] over the VF layout.
// ---------------------------------------------------------------------------
__global__ __launch_bounds__(256) void k_red(
    const uint* __restrict__ Q, const uint* __restrict__ Kk,
    const u16* __restrict__ VT, float* __restrict__ diagv,
    float* __restrict__ colsum) {
  const int bid = blockIdx.x, tid = threadIdx.x;
  __shared__ float red[256];
  if (bid < 8) {
    const int b = bid;
    const int hh = tid >> 5, dd = tid & 31;
    const uint* qb = Q + (size_t)(b * HEADS + hh) * NPIX * (D / 2);
    const uint* kb = Kk + (size_t)(b * HEADS + hh) * NPIX * (D / 2);
    float s = 0.f;
#pragma unroll 4
    for (int t = 0; t < 32; ++t) {
      uint qu = qb[t * 33 * (D / 2) + dd / 2];
      uint ku = kb[t * 33 * (D / 2) + dd / 2];
      float qv = (dd & 1) ? bf_hi(qu) : bf_lo(qu);
      float kv = (dd & 1) ? bf_hi(ku) : bf_lo(ku);
      s += qv * kv;
    }
    red[tid] = s;
    __syncthreads();
    if (tid < 32) {
      float v = 0.f;
#pragma unroll
      for (int h8 = 0; h8 < 8; ++h8) v += red[h8 * 32 + tid];
      diagv[b * 32 + tid] = v * (0.125f / LOG2E);
    }
  } else {
    const int bh = bid - 8;
    const int d = tid >> 3, sl = tid & 7;
    const int nta = d >> 4, l15a = d & 15;
    const u16* vb = VT + (size_t)bh * NPIX * D;
    float s = 0.f;
    for (int jb = 0; jb < 8; ++jb) {
      const int jb16 = sl * 8 + jb;
#pragma unroll
      for (int qa = 0; qa < 4; ++qa) {
        const uint2 u = *(const uint2*)(
            vb + ((size_t)(jb16 * 2 + nta) * 64 + qa * 16 + l15a) * 4);
        s += bf_lo(u.x) + bf_hi(u.x) + bf_lo(u.y) + bf_hi(u.y);
      }
    }
    red[tid] = s;
    __syncthreads();
    if (tid < 32) {
      float v = 0.f;
#pragma unroll
      for (int g = 0; g < 8; ++g) v += red[tid * 8 + g];
      colsum[bh * D + tid] = v;
    }
  }
}

// ---------------------------------------------------------------------------
// K2: MFMA flash attention — cross-lane-free inner loop, coalesced V,
// XCD-aware bh partitioning + 2x unrolled j-loop for MLP.
// 1D grid of 1024 blocks, 4 waves; assuming round-robin block->XCD
// dispatch (id%8), XCD x runs ONLY bh in [8x, 8x+8): per-XCD K/V+Q
// working set ~1.5MB fits the 4MB L2 (was ~12MB thrash -> HBM latency).
// S^T via mfma16x16x32(K,Q); PV via mfma_f32_16x16x16bf16_1k (P^T layout
// == A-frag, zero cross-lane). No in-loop setprio (scheduler freedom).
// ---------------------------------------------------------------------------
__global__ __launch_bounds__(256, 4) void k_attn(
    const u16* __restrict__ Q, const u16* __restrict__ Kk,
    const u16* __restrict__ VT, const float* __restrict__ diagv,
    const float* __restrict__ colsum, u16* __restrict__ AOT) {
  const int bx = blockIdx.x;                 // 0..1023
  const int xcd = bx & 7, slot = bx >> 3;    // bijective swizzle
  const int bh = xcd * 8 + (slot & 7);       // 0..63, octet per XCD
  const int qc = slot >> 3;                  // 0..15
  const int b = bh >> 3, hh = bh & 7;
  const int wv = threadIdx.x >> 6, lane = threadIdx.x & 63;
  const int quad = lane >> 4, l15 = lane & 15;
  const int i0 = qc * 64 + wv * 16;

  const u16* Qb  = Q  + (size_t)bh * NPIX * D;
  const u16* Kb  = Kk + (size_t)bh * NPIX * D;
  const u16* VFb = VT + (size_t)bh * NPIX * D;

  bf16x8 qfrag = *(const bf16x8*)(Qb + (size_t)(i0 + l15) * D + quad * 8);

  f32x4 oacc[2];
  oacc[0] = (f32x4){0.f, 0.f, 0.f, 0.f};
  oacc[1] = (f32x4){0.f, 0.f, 0.f, 0.f};
  float lacc[4] = {};

  const u16* kp  = Kb + (size_t)l15 * D + quad * 8;   // + j*D
  const u16* vfp = VFb + (size_t)lane * 4;            // + (jb16*2+nt)*256

#pragma unroll 2
  for (int it = 0; it < 16; ++it) {
    // V fragments: 8 fully-coalesced 8B/lane loads (512B burst each)
    bf16x4 vf[4][2];
#pragma unroll
    for (int jt = 0; jt < 4; ++jt)
#pragma unroll
      for (int nt = 0; nt < 2; ++nt)
        vf[jt][nt] = *(const bf16x4*)(
            vfp + (size_t)(((it * 4 + jt) * 2 + nt) * 256));

    // S^T = K Q^T: lane holds P^T rows j = jt*16+quad*4+r, col i = l15
    f32x4 st[4];
#pragma unroll
    for (int jt = 0; jt < 4; ++jt) {
      bf16x8 kfrag = *(const bf16x8*)(kp + (size_t)(it * 64 + jt * 16) * D);
      st[jt] = __builtin_amdgcn_mfma_f32_16x16x32_bf16(
          kfrag, qfrag, (f32x4){0.f, 0.f, 0.f, 0.f}, 0, 0, 0);
    }

    // exp (arg pre-scaled by SCALE*LOG2E at QKV time) + row-sum accumulate
#pragma unroll
    for (int jt = 0; jt < 4; ++jt)
#pragma unroll
      for (int r = 0; r < 4; ++r) {
        float pv = exp2f(fminf(st[jt][r], 80.f));
        lacc[r] += pv;
        st[jt][r] = pv;
      }

    // pack P in-register (A-frag of K=16 MFMA) + PV, no cross-lane movement
#pragma unroll
    for (int jt = 0; jt < 4; ++jt) {
      union { uint u[2]; bf16x4 v; } pa;
      pa.u[0] = pk2(st[jt][0], st[jt][1]);
      pa.u[1] = pk2(st[jt][2], st[jt][3]);
#pragma unroll
      for (int nt = 0; nt < 2; ++nt)
        oacc[nt] = __builtin_amdgcn_mfma_f32_16x16x16bf16_1k(
            pa.v, vf[jt][nt], oacc[nt], 0, 0, 0);
    }
  }

  // row-sum: lane already has 16 j-classes for its row; reduce across quads
  float lt = (lacc[0] + lacc[1]) + (lacc[2] + lacc[3]);
  lt += __shfl_xor(lt, 16, 64);
  lt += __shfl_xor(lt, 32, 64);
  const float linv = 1.f / lt;
  // oacc rows are i = quad*4+r; fetch 1/l from lane l15 = quad*4+r
  float rinv[4];
#pragma unroll
  for (int r = 0; r < 4; ++r) rinv[r] = __shfl(linv, quad * 4 + r, 64);

  // epilogue: normalize, diag term (rows < 32), store AOT[b][pix][ch]
  const bool do_diag = (i0 < 32);
#pragma unroll
  for (int nt = 0; nt < 2; ++nt) {
    const int dch = hh * 32 + nt * 16 + l15;
    float cs = do_diag ? colsum[bh * D + (nt * 16 + l15)] : 0.f;
#pragma unroll
    for (int r = 0; r < 4; ++r) {
      const int irow = i0 + quad * 4 + r;
      float o = oacc[nt][r] * rinv[r];
      if (do_diag) o += 0.3f * diagv[b * 32 + irow] * cs;
      AOT[((size_t)b * NPIX + irow) * C + dch] = f2bf(o);
    }
  }
}

// ---------------------------------------------------------------------------
// K3: gate. One block per (b, row h); 16 distinct gate values per row.
// ---------------------------------------------------------------------------
__global__ __launch_bounds__(256) void k_gate(
    const float* __restrict__ x,
    const float* __restrict__ wg1, const float* __restrict__ bg1,
    const float* __restrict__ wg2, const float* __restrict__ bg2,
    float* __restrict__ gate) {
  const int h = blockIdx.x, b = blockIdx.y, tid = threadIdx.x;
  __shared__ float pl[16 * 257];
  __shared__ float gl[16 * 65];

  {
    const int c = tid;
    const float* row = x + ((size_t)(b * C + c) * NPIX + h * 32);
    float v[32];
#pragma unroll
    for (int m = 0; m < 32; ++m) v[m] = row[m];
#pragma unroll
    for (int k = 0; k < 16; ++k) pl[k * 257 + c] = fabsf(v[k] - v[31 - k]);
  }
  __syncthreads();

  const int o16 = tid >> 4, k = tid & 15;
#pragma unroll 1
  for (int p = 0; p < 4; ++p) {
    const int o = p * 16 + o16;
    const float* wr = wg1 + o * C;
    float a0 = 0.f, a1 = 0.f, a2 = 0.f, a3 = 0.f;
#pragma unroll 4
    for (int c = 0; c < C; c += 4) {
      a0 += wr[c]     * pl[k * 257 + c];
      a1 += wr[c + 1] * pl[k * 257 + c + 1];
      a2 += wr[c + 2] * pl[k * 257 + c + 2];
      a3 += wr[c + 3] * pl[k * 257 + c + 3];
    }
    float a = bg1[o] + ((a0 + a1) + (a2 + a3));
    gl[k * 65 + o] = 0.5f * a * (1.f + erff(a * 0.70710678118654752f));
  }
  __syncthreads();

  if (tid < 16) {
    float s = bg2[0];
    for (int o = 0; o < 64; ++o)
      s += wg2[o] * gl[tid * 65 + o];
    gate[(b * 32 + h) * 16 + tid] = 1.f / (1.f + expf(-s));
  }
}

// ---------------------------------------------------------------------------
// K4: output GEMM via MFMA, gate+bias fused. out fp32 [b][o][pix].
// ---------------------------------------------------------------------------
__global__ __launch_bounds__(256) void k_out_mfma(
    const u16* __restrict__ AOT, const u16* __restrict__ WO,
    const float* __restrict__ bout, const float* __restrict__ gate,
    float* __restrict__ out) {
  const int ob = blockIdx.x, pb = blockIdx.y, b = blockIdx.z;
  const int wv = threadIdx.x >> 6, lane = threadIdx.x & 63;
  const int quad = lane >> 4, l15 = lane & 15;
  const int o0 = ob * 64 + wv * 16;
  const int pix0 = pb * 128;

  const u16* arow = WO + (size_t)(o0 + l15) * C;
  bf16x8 af[8];
#pragma unroll
  for (int kc = 0; kc < 8; ++kc)
    af[kc] = *(const bf16x8*)(arow + kc * 32 + quad * 8);

  const u16* ab = AOT + (size_t)(b * NPIX + pix0) * C;
  f32x4 acc[8];
#pragma unroll
  for (int nt = 0; nt < 8; ++nt) acc[nt] = (f32x4){0.f, 0.f, 0.f, 0.f};

  for (int kc = 0; kc < 8; ++kc) {
#pragma unroll
    for (int nt = 0; nt < 8; ++nt) {
      bf16x8 bfr = *(const bf16x8*)(ab + (size_t)(nt * 16 + l15) * C +
                                    kc * 32 + quad * 8);
      acc[nt] = __builtin_amdgcn_mfma_f32_16x16x32_bf16(af[kc], bfr, acc[nt], 0, 0, 0);
    }
  }

#pragma unroll
  for (int nt = 0; nt < 8; ++nt) {
    const int pix = pix0 + nt * 16 + l15;
    const float gf = 1.f + gate[(b * 32 + (pix >> 5)) * 16 + ((pix & 31) >> 1)];
#pragma unroll
    for (int r = 0; r < 4; ++r) {
      const int o = o0 + 4 * quad + r;
      out[((size_t)b * C + o) * NPIX + pix] = acc[nt][r] * gf + bout[o];
    }
  }
}

// ---------------------------------------------------------------------------
extern "C" void kernel_launch(void* const* d_in, const int* in_sizes, int n_in,
                              void* d_out, int out_size, void* d_ws, size_t ws_size,
                              hipStream_t stream) {
  const float* x    = (const float*)d_in[0];
  const float* wqkv = (const float*)d_in[1];
  const float* wout = (const float*)d_in[2];
  const float* bout = (const float*)d_in[3];
  const float* wg1  = (const float*)d_in[4];
  const float* bg1  = (const float*)d_in[5];
  const float* wg2  = (const float*)d_in[6];
  const float* bg2  = (const float*)d_in[7];
  float* out = (float*)d_out;

  const size_t SZ = (size_t)B * HEADS * NPIX * D;   // 2,097,152
  u16* XT = (u16*)d_ws;
  u16* WQ = XT + SZ;
  u16* WO = WQ + (size_t)OC * C;
  u16* Q  = WO + (size_t)C * C;
  u16* Kq = Q + SZ;
  u16* VT = Kq + SZ;
  float* DIAG = (float*)(VT + SZ);
  float* COL  = DIAG + 256;
  float* GATE = COL + 2048;
  u16* AOT = XT;   // alias: XT dead after k_qkv_mfma

  hipLaunchKernelGGL(k_prep, dim3(768), dim3(256), 0, stream,
                     x, wqkv, wout, WQ, WO, XT);
  hipLaunchKernelGGL(k_qkv_mfma, dim3(12, 8, B), dim3(256), 0, stream,
                     XT, WQ, Q, Kq, VT);
  hipLaunchKernelGGL(k_red, dim3(72), dim3(256), 0, stream,
                     (const uint*)Q, (const uint*)Kq, VT, DIAG, COL);
  hipLaunchKernelGGL(k_attn, dim3(1024), dim3(256), 0, stream,
                     Q, Kq, VT, DIAG, COL, AOT);
  hipLaunchKernelGGL(k_gate, dim3(32, B), dim3(256), 0, stream,
                     x, wg1, bg1, wg2, bg2, GATE);
  hipLaunchKernelGGL(k_out_mfma, dim3(4, 8, B), dim3(256), 0, stream,
                     AOT, WO, bout, GATE, out);
}

// Round 8
// 169.046 us; speedup vs baseline: 1.0485x; 1.0485x over previous
//
#include <hip/hip_runtime.h>
#include <hip/hip_bf16.h>
#include <math.h>

#define B 8
#define C 256
#define HEADS 8
#define D 32
#define NPIX 1024
#define OC 768
#define SCALE 0.17677669529663687f   // 1/sqrt(32)
#define LOG2E 1.4426950408889634f

typedef unsigned int uint;
typedef unsigned short u16;
typedef __attribute__((ext_vector_type(8))) short bf16x8;
typedef __attribute__((ext_vector_type(4))) short bf16x4;
typedef __attribute__((ext_vector_type(4))) float f32x4;

static __device__ inline u16 f2bf(float f) {   // RNE f32->bf16
  uint u = __float_as_uint(f);
  return (u16)((u + 0x7fffu + ((u >> 16) & 1u)) >> 16);
}
static __device__ inline float bfval(u16 v) { return __uint_as_float((uint)v << 16); }
static __device__ inline float bf_lo(uint u) { return __uint_as_float(u << 16); }
static __device__ inline float bf_hi(uint u) { return __uint_as_float(u & 0xffff0000u); }

// packed f32x2 -> bf16x2 (lowers to v_cvt_pk_bf16_f32 on gfx950)
static __device__ inline uint pk2(float lo, float hi) {
  union { __hip_bfloat162 h; uint u; } cv;
  cv.h = __float22bfloat162_rn(float2{lo, hi});
  return cv.u;
}

// ---------------------------------------------------------------------------
// P0: fused prep. Blocks [0,256): weights fp32->bf16 (wqkv then wout).
// Blocks [256,768): transpose-convert x[b][c][pix] -> XT[b][pix][c] bf16.
// ---------------------------------------------------------------------------
__global__ __launch_bounds__(256) void k_prep(
    const float* __restrict__ x, const float* __restrict__ wqkv,
    const float* __restrict__ wout,
    u16* __restrict__ WQ, u16* __restrict__ WO, u16* __restrict__ XT) {
  const int bid = blockIdx.x, t = threadIdx.x;
  __shared__ u16 tile[64][65];
  if (bid < 256) {
    const float* src;
    u16* dst;
    int base;
    if (bid < 192) { src = wqkv; dst = WQ; base = bid * 1024; }
    else           { src = wout; dst = WO; base = (bid - 192) * 1024; }
    float4 v = *(const float4*)(src + base + t * 4);
    uint2 pk = make_uint2((uint)f2bf(v.x) | ((uint)f2bf(v.y) << 16),
                          (uint)f2bf(v.z) | ((uint)f2bf(v.w) << 16));
    *(uint2*)(dst + base + t * 4) = pk;
    return;
  }
  const int id = bid - 256;
  const int pt = id & 15, ct = (id >> 4) & 3, b = id >> 6;
  {
    const int px = t & 63, cq = t >> 6;
    const float* xb = x + ((size_t)(b * C + ct * 64)) * NPIX + pt * 64;
#pragma unroll
    for (int m = 0; m < 16; ++m) {
      const int c = cq * 16 + m;
      tile[c][px] = f2bf(xb[(size_t)c * NPIX + px]);
    }
  }
  __syncthreads();
  {
    const int cc = t & 63, pq = t >> 6;
    u16* dst = XT + ((size_t)(b * NPIX + pt * 64)) * C + ct * 64;
#pragma unroll
    for (int m = 0; m < 16; ++m) {
      const int pix = pq * 16 + m;
      dst[(size_t)pix * C + cc] = tile[cc][pix];
    }
  }
}

// ---------------------------------------------------------------------------
// K1: QKV GEMM via MFMA. D[o][pix] = W[o][c] . XT[pix][c]^T.
// Q pre-scaled by SCALE*LOG2E, row-major (k_red diag compensates).
// K and V stored in FRAGMENT-ORDER layouts so k_attn can stage whole 64-j
// tiles as contiguous 4KB chunks and read fragments contiguously per lane:
//   KF[bh][ (j>>4)*512 + ((d>>3)*16 + (j&15))*8 + (d&7) ]         = K[j][d]
//   VF[bh][ (j>>4)*512 + (((j>>2)&3)*16 + (d&15))*4*? ] -- as below:
//   VF[bh][ ((j>>4)*2 + (d>>4))*256 + (((j>>2)&3)*16 + (d&15))*4 + (j&3) ]
// ---------------------------------------------------------------------------
__global__ __launch_bounds__(256) void k_qkv_mfma(
    const u16* __restrict__ XT, const u16* __restrict__ WQ,
    u16* __restrict__ Q, u16* __restrict__ Kk, u16* __restrict__ VT) {
  const int ob = blockIdx.x, pb = blockIdx.y, b = blockIdx.z;
  const int wv = threadIdx.x >> 6, lane = threadIdx.x & 63;
  const int quad = lane >> 4, l15 = lane & 15;
  const int part = ob >> 2;
  const int odl = (ob & 3) * 64 + wv * 16;
  const int hh = odl >> 5, d0 = odl & 31;
  const int bh = b * HEADS + hh;
  const int pix0 = pb * 128;

  const u16* arow = WQ + (size_t)(ob * 64 + wv * 16 + l15) * C;
  bf16x8 af[8];
#pragma unroll
  for (int kc = 0; kc < 8; ++kc)
    af[kc] = *(const bf16x8*)(arow + kc * 32 + quad * 8);

  const u16* xb = XT + (size_t)(b * NPIX + pix0) * C;
  f32x4 acc[8];
#pragma unroll
  for (int nt = 0; nt < 8; ++nt) acc[nt] = (f32x4){0.f, 0.f, 0.f, 0.f};

  for (int kc = 0; kc < 8; ++kc) {
#pragma unroll
    for (int nt = 0; nt < 8; ++nt) {
      bf16x8 bfr = *(const bf16x8*)(xb + (size_t)(nt * 16 + l15) * C +
                                    kc * 32 + quad * 8);
      acc[nt] = __builtin_amdgcn_mfma_f32_16x16x32_bf16(af[kc], bfr, acc[nt], 0, 0, 0);
    }
  }

  if (part == 0) {
    const float qs = SCALE * LOG2E;
    u16* dst = Q + (size_t)bh * NPIX * D;
#pragma unroll
    for (int nt = 0; nt < 8; ++nt) {
      const int pix = pix0 + nt * 16 + l15;
      uint2 pk = make_uint2(
          (uint)f2bf(acc[nt][0] * qs) | ((uint)f2bf(acc[nt][1] * qs) << 16),
          (uint)f2bf(acc[nt][2] * qs) | ((uint)f2bf(acc[nt][3] * qs) << 16));
      *(uint2*)(dst + (size_t)pix * D + d0 + 4 * quad) = pk;
    }
  } else if (part == 1) {
    // KF fragment-order: rows o = d0+4*quad+r, r=0..3 land in one uint2
    u16* kfb = Kk + (size_t)bh * NPIX * D;
    const int lane_k8 = (((d0 >> 3) + (quad >> 1)) * 16 + l15) * 8 + (quad & 1) * 4;
#pragma unroll
    for (int nt = 0; nt < 8; ++nt) {
      uint2 pk = make_uint2(
          (uint)f2bf(acc[nt][0]) | ((uint)f2bf(acc[nt][1]) << 16),
          (uint)f2bf(acc[nt][2]) | ((uint)f2bf(acc[nt][3]) << 16));
      *(uint2*)(kfb + (size_t)(pb * 8 + nt) * 512 + lane_k8) = pk;
    }
  } else {
    u16* vb = VT + (size_t)bh * NPIX * D;
#pragma unroll
    for (int nt = 0; nt < 8; ++nt) {
      const int pix = pix0 + nt * 16 + l15;           // j
      const int jb16 = pix >> 4, qa = (pix >> 2) & 3, m = pix & 3;
#pragma unroll
      for (int r = 0; r < 4; ++r) {
        const int d = d0 + 4 * quad + r;              // 0..31
        const int nta = d >> 4, l15a = d & 15;
        vb[((size_t)(jb16 * 2 + nta) * 64 + qa * 16 + l15a) * 4 + m] =
            f2bf(acc[nt][r]);
      }
    }
  }
}

// ---------------------------------------------------------------------------
// R: fused reductions. Blocks [0,8): diag_vec[b] (Q carries SCALE*LOG2E, so
// final factor is 0.125/LOG2E; K read via KF layout). Blocks [8,72):
// colsum[bh] over the VF layout.
// ---------------------------------------------------------------------------
__global__ __launch_bounds__(256) void k_red(
    const u16* __restrict__ Q, const u16* __restrict__ KF,
    const u16* __restrict__ VT, float* __restrict__ diagv,
    float* __restrict__ colsum) {
  const int bid = blockIdx.x, tid = threadIdx.x;
  __shared__ float red[256];
  if (bid < 8) {
    const int b = bid;
    const int hh = tid >> 5, dd = tid & 31;
    const u16* qb = Q + (size_t)(b * HEADS + hh) * NPIX * D;
    const u16* kb = KF + (size_t)(b * HEADS + hh) * NPIX * D;
    float s = 0.f;
#pragma unroll 4
    for (int t = 0; t < 32; ++t) {
      const int j = t * 33;
      float qv = bfval(qb[(size_t)j * D + dd]);
      float kv = bfval(kb[(size_t)(j >> 4) * 512 +
                          ((dd >> 3) * 16 + (j & 15)) * 8 + (dd & 7)]);
      s += qv * kv;
    }
    red[tid] = s;
    __syncthreads();
    if (tid < 32) {
      float v = 0.f;
#pragma unroll
      for (int h8 = 0; h8 < 8; ++h8) v += red[h8 * 32 + tid];
      diagv[b * 32 + tid] = v * (0.125f / LOG2E);
    }
  } else {
    const int bh = bid - 8;
    const int d = tid >> 3, sl = tid & 7;
    const int nta = d >> 4, l15a = d & 15;
    const u16* vb = VT + (size_t)bh * NPIX * D;
    float s = 0.f;
    for (int jb = 0; jb < 8; ++jb) {
      const int jb16 = sl * 8 + jb;
#pragma unroll
      for (int qa = 0; qa < 4; ++qa) {
        const uint2 u = *(const uint2*)(
            vb + ((size_t)(jb16 * 2 + nta) * 64 + qa * 16 + l15a) * 4);
        s += bf_lo(u.x) + bf_hi(u.x) + bf_lo(u.y) + bf_hi(u.y);
      }
    }
    red[tid] = s;
    __syncthreads();
    if (tid < 32) {
      float v = 0.f;
#pragma unroll
      for (int g = 0; g < 8; ++g) v += red[tid * 8 + g];
      colsum[bh * D + tid] = v;
    }
  }
}

// ---------------------------------------------------------------------------
// K2: MFMA flash attention with block-shared double-buffered LDS staging.
// All 4 waves consume IDENTICAL K/V tiles; each wave reg-stages 2KB of the
// next 8KB tile (coalesced 1KB global loads -> contiguous ds_write_b128),
// 1 barrier/iter. Fragment reads are contiguous-per-lane ds_read_b128/b64
// (KF/VF fragment-order layouts). S^T via mfma16x16x32(K,Q); PV via
// mfma_f32_16x16x16bf16_1k (P^T == A-frag, zero cross-lane).
// Grid (16 qchunks of 64, 64 bh), 4 waves; wave owns 16 q-rows.
// ---------------------------------------------------------------------------
__global__ __launch_bounds__(256, 4) void k_attn(
    const u16* __restrict__ Q, const u16* __restrict__ KF,
    const u16* __restrict__ VF, const float* __restrict__ diagv,
    const float* __restrict__ colsum, u16* __restrict__ AOT) {
  const int qc = blockIdx.x;           // 0..15
  const int bh = blockIdx.y;           // 0..63
  const int b = bh >> 3, hh = bh & 7;
  const int wv = threadIdx.x >> 6, lane = threadIdx.x & 63;
  const int quad = lane >> 4, l15 = lane & 15;
  const int i0 = qc * 64 + wv * 16;

  __shared__ u16 sbuf[2][4096];        // 2 x 8KB: [K 4KB | V 4KB]

  const u16* Qb  = Q  + (size_t)bh * NPIX * D;
  const u16* KFb = KF + (size_t)bh * NPIX * D;
  const u16* VFb = VF + (size_t)bh * NPIX * D;

  bf16x8 qfrag = *(const bf16x8*)(Qb + (size_t)(i0 + l15) * D + quad * 8);

  f32x4 oacc[2];
  oacc[0] = (f32x4){0.f, 0.f, 0.f, 0.f};
  oacc[1] = (f32x4){0.f, 0.f, 0.f, 0.f};
  float lacc[4] = {};

  // staging role: waves 0,1 copy the K tile halves, waves 2,3 the V tile
  const u16* gsrc = (wv < 2 ? KFb : VFb) + (wv & 1) * 1024 + lane * 8;
  u16* ldst[2] = { &sbuf[0][wv * 1024 + lane * 8],
                   &sbuf[1][wv * 1024 + lane * 8] };

  // prologue: stage tile 0 into buffer 0
  {
    uint4 a = *(const uint4*)(gsrc);
    uint4 c = *(const uint4*)(gsrc + 512);
    *(uint4*)(ldst[0]) = a;
    *(uint4*)(ldst[0] + 512) = c;
  }
  __syncthreads();

  int cur = 0;
  for (int it = 0; it < 16; ++it) {
    // prefetch next tile into the other buffer (hidden under compute)
    if (it < 15) {
      uint4 a = *(const uint4*)(gsrc + (size_t)(it + 1) * 2048);
      uint4 c = *(const uint4*)(gsrc + (size_t)(it + 1) * 2048 + 512);
      u16* ld = ldst[cur ^ 1];
      *(uint4*)(ld) = a;
      *(uint4*)(ld + 512) = c;
    }
    const u16* sK = &sbuf[cur][0];
    const u16* sV = &sbuf[cur][2048];

    // S^T = K Q^T: lane holds P^T rows j = jt*16+quad*4+r, col i = l15
    f32x4 st[4];
#pragma unroll
    for (int jt = 0; jt < 4; ++jt) {
      bf16x8 kfrag = *(const bf16x8*)(sK + jt * 512 + lane * 8);
      st[jt] = __builtin_amdgcn_mfma_f32_16x16x32_bf16(
          kfrag, qfrag, (f32x4){0.f, 0.f, 0.f, 0.f}, 0, 0, 0);
    }

    // exp (arg pre-scaled by SCALE*LOG2E at QKV time) + row-sum accumulate
#pragma unroll
    for (int jt = 0; jt < 4; ++jt)
#pragma unroll
      for (int r = 0; r < 4; ++r) {
        float pv = exp2f(fminf(st[jt][r], 80.f));
        lacc[r] += pv;
        st[jt][r] = pv;
      }

    // pack P in-register (A-frag of K=16 MFMA) + PV, no cross-lane movement
    __builtin_amdgcn_s_setprio(1);
#pragma unroll
    for (int jt = 0; jt < 4; ++jt) {
      union { uint u[2]; bf16x4 v; } pa;
      pa.u[0] = pk2(st[jt][0], st[jt][1]);
      pa.u[1] = pk2(st[jt][2], st[jt][3]);
#pragma unroll
      for (int nt = 0; nt < 2; ++nt) {
        bf16x4 vfr = *(const bf16x4*)(sV + (jt * 2 + nt) * 256 + lane * 4);
        oacc[nt] = __builtin_amdgcn_mfma_f32_16x16x16bf16_1k(
            pa.v, vfr, oacc[nt], 0, 0, 0);
      }
    }
    __builtin_amdgcn_s_setprio(0);

    __syncthreads();   // staged writes visible; all waves done with cur
    cur ^= 1;
  }

  // row-sum: lane already has 16 j-classes for its row; reduce across quads
  float lt = (lacc[0] + lacc[1]) + (lacc[2] + lacc[3]);
  lt += __shfl_xor(lt, 16, 64);
  lt += __shfl_xor(lt, 32, 64);
  const float linv = 1.f / lt;
  // oacc rows are i = quad*4+r; fetch 1/l from lane l15 = quad*4+r
  float rinv[4];
#pragma unroll
  for (int r = 0; r < 4; ++r) rinv[r] = __shfl(linv, quad * 4 + r, 64);

  // epilogue: normalize, diag term (rows < 32), store AOT[b][pix][ch]
  const bool do_diag = (i0 < 32);
#pragma unroll
  for (int nt = 0; nt < 2; ++nt) {
    const int dch = hh * 32 + nt * 16 + l15;
    float cs = do_diag ? colsum[bh * D + (nt * 16 + l15)] : 0.f;
#pragma unroll
    for (int r = 0; r < 4; ++r) {
      const int irow = i0 + quad * 4 + r;
      float o = oacc[nt][r] * rinv[r];
      if (do_diag) o += 0.3f * diagv[b * 32 + irow] * cs;
      AOT[((size_t)b * NPIX + irow) * C + dch] = f2bf(o);
    }
  }
}

// ---------------------------------------------------------------------------
// K3: gate. One block per (b, row h); 16 distinct gate values per row.
// ---------------------------------------------------------------------------
__global__ __launch_bounds__(256) void k_gate(
    const float* __restrict__ x,
    const float* __restrict__ wg1, const float* __restrict__ bg1,
    const float* __restrict__ wg2, const float* __restrict__ bg2,
    float* __restrict__ gate) {
  const int h = blockIdx.x, b = blockIdx.y, tid = threadIdx.x;
  __shared__ float pl[16 * 257];
  __shared__ float gl[16 * 65];

  {
    const int c = tid;
    const float* row = x + ((size_t)(b * C + c) * NPIX + h * 32);
    float v[32];
#pragma unroll
    for (int m = 0; m < 32; ++m) v[m] = row[m];
#pragma unroll
    for (int k = 0; k < 16; ++k) pl[k * 257 + c] = fabsf(v[k] - v[31 - k]);
  }
  __syncthreads();

  const int o16 = tid >> 4, k = tid & 15;
#pragma unroll 1
  for (int p = 0; p < 4; ++p) {
    const int o = p * 16 + o16;
    const float* wr = wg1 + o * C;
    float a0 = 0.f, a1 = 0.f, a2 = 0.f, a3 = 0.f;
#pragma unroll 4
    for (int c = 0; c < C; c += 4) {
      a0 += wr[c]     * pl[k * 257 + c];
      a1 += wr[c + 1] * pl[k * 257 + c + 1];
      a2 += wr[c + 2] * pl[k * 257 + c + 2];
      a3 += wr[c + 3] * pl[k * 257 + c + 3];
    }
    float a = bg1[o] + ((a0 + a1) + (a2 + a3));
    gl[k * 65 + o] = 0.5f * a * (1.f + erff(a * 0.70710678118654752f));
  }
  __syncthreads();

  if (tid < 16) {
    float s = bg2[0];
    for (int o = 0; o < 64; ++o)
      s += wg2[o] * gl[tid * 65 + o];
    gate[(b * 32 + h) * 16 + tid] = 1.f / (1.f + expf(-s));
  }
}

// ---------------------------------------------------------------------------
// K4: output GEMM via MFMA, gate+bias fused. out fp32 [b][o][pix].
// ---------------------------------------------------------------------------
__global__ __launch_bounds__(256) void k_out_mfma(
    const u16* __restrict__ AOT, const u16* __restrict__ WO,
    const float* __restrict__ bout, const float* __restrict__ gate,
    float* __restrict__ out) {
  const int ob = blockIdx.x, pb = blockIdx.y, b = blockIdx.z;
  const int wv = threadIdx.x >> 6, lane = threadIdx.x & 63;
  const int quad = lane >> 4, l15 = lane & 15;
  const int o0 = ob * 64 + wv * 16;
  const int pix0 = pb * 128;

  const u16* arow = WO + (size_t)(o0 + l15) * C;
  bf16x8 af[8];
#pragma unroll
  for (int kc = 0; kc < 8; ++kc)
    af[kc] = *(const bf16x8*)(arow + kc * 32 + quad * 8);

  const u16* ab = AOT + (size_t)(b * NPIX + pix0) * C;
  f32x4 acc[8];
#pragma unroll
  for (int nt = 0; nt < 8; ++nt) acc[nt] = (f32x4){0.f, 0.f, 0.f, 0.f};

  for (int kc = 0; kc < 8; ++kc) {
#pragma unroll
    for (int nt = 0; nt < 8; ++nt) {
      bf16x8 bfr = *(const bf16x8*)(ab + (size_t)(nt * 16 + l15) * C +
                                    kc * 32 + quad * 8);
      acc[nt] = __builtin_amdgcn_mfma_f32_16x16x32_bf16(af[kc], bfr, acc[nt], 0, 0, 0);
    }
  }

#pragma unroll
  for (int nt = 0; nt < 8; ++nt) {
    const int pix = pix0 + nt * 16 + l15;
    const float gf = 1.f + gate[(b * 32 + (pix >> 5)) * 16 + ((pix & 31) >> 1)];
#pragma unroll
    for (int r = 0; r < 4; ++r) {
      const int o = o0 + 4 * quad + r;
      out[((size_t)b * C + o) * NPIX + pix] = acc[nt][r] * gf + bout[o];
    }
  }
}

// ---------------------------------------------------------------------------
extern "C" void kernel_launch(void* const* d_in, const int* in_sizes, int n_in,
                              void* d_out, int out_size, void* d_ws, size_t ws_size,
                              hipStream_t stream) {
  const float* x    = (const float*)d_in[0];
  const float* wqkv = (const float*)d_in[1];
  const float* wout = (const float*)d_in[2];
  const float* bout = (const float*)d_in[3];
  const float* wg1  = (const float*)d_in[4];
  const float* bg1  = (const float*)d_in[5];
  const float* wg2  = (const float*)d_in[6];
  const float* bg2  = (const float*)d_in[7];
  float* out = (float*)d_out;

  const size_t SZ = (size_t)B * HEADS * NPIX * D;   // 2,097,152
  u16* XT = (u16*)d_ws;
  u16* WQ = XT + SZ;
  u16* WO = WQ + (size_t)OC * C;
  u16* Q  = WO + (size_t)C * C;
  u16* Kq = Q + SZ;
  u16* VT = Kq + SZ;
  float* DIAG = (float*)(VT + SZ);
  float* COL  = DIAG + 256;
  float* GATE = COL + 2048;
  u16* AOT = XT;   // alias: XT dead after k_qkv_mfma

  hipLaunchKernelGGL(k_prep, dim3(768), dim3(256), 0, stream,
                     x, wqkv, wout, WQ, WO, XT);
  hipLaunchKernelGGL(k_qkv_mfma, dim3(12, 8, B), dim3(256), 0, stream,
                     XT, WQ, Q, Kq, VT);
  hipLaunchKernelGGL(k_red, dim3(72), dim3(256), 0, stream,
                     Q, Kq, VT, DIAG, COL);
  hipLaunchKernelGGL(k_attn, dim3(16, 64), dim3(256), 0, stream,
                     Q, Kq, VT, DIAG, COL, AOT);
  hipLaunchKernelGGL(k_gate, dim3(32, B), dim3(256), 0, stream,
                     x, wg1, bg1, wg2, bg2, GATE);
  hipLaunchKernelGGL(k_out_mfma, dim3(4, 8, B), dim3(256), 0, stream,
                     AOT, WO, bout, GATE, out);
}

// Round 9
// 156.395 us; speedup vs baseline: 1.1334x; 1.0809x over previous
//
#include <hip/hip_runtime.h>
#include <hip/hip_bf16.h>
#include <math.h>

#define B 8
#define C 256
#define HEADS 8
#define D 32
#define NPIX 1024
#define OC 768
#define SCALE 0.17677669529663687f   // 1/sqrt(32)
#define LOG2E 1.4426950408889634f

typedef unsigned int uint;
typedef unsigned short u16;
typedef __attribute__((ext_vector_type(8))) short bf16x8;
typedef __attribute__((ext_vector_type(4))) short bf16x4;
typedef __attribute__((ext_vector_type(4))) float f32x4;

static __device__ inline u16 f2bf(float f) {   // RNE f32->bf16
  uint u = __float_as_uint(f);
  return (u16)((u + 0x7fffu + ((u >> 16) & 1u)) >> 16);
}
static __device__ inline float bfval(u16 v) { return __uint_as_float((uint)v << 16); }
static __device__ inline float bf_lo(uint u) { return __uint_as_float(u << 16); }
static __device__ inline float bf_hi(uint u) { return __uint_as_float(u & 0xffff0000u); }

// packed f32x2 -> bf16x2 (lowers to v_cvt_pk_bf16_f32 on gfx950)
static __device__ inline uint pk2(float lo, float hi) {
  union { __hip_bfloat162 h; uint u; } cv;
  cv.h = __float22bfloat162_rn(float2{lo, hi});
  return cv.u;
}

// ---------------------------------------------------------------------------
// P0: fused prep. Blocks [0,256): weights fp32->bf16 (wqkv then wout).
// Blocks [256,768): transpose-convert x[b][c][pix] into FRAGMENT-ORDER
// XTF so k_qkv's B-fragment loads are contiguous 1KB bursts:
//   XTF[((b*64 + p16)*8 + kc)*512 + (quad*16 + l15)*8 + mm]
//     = x_bf16[pix = p16*16 + l15][c = kc*32 + quad*8 + mm]
// ---------------------------------------------------------------------------
__global__ __launch_bounds__(256) void k_prep(
    const float* __restrict__ x, const float* __restrict__ wqkv,
    const float* __restrict__ wout,
    u16* __restrict__ WQ, u16* __restrict__ WO, u16* __restrict__ XT) {
  const int bid = blockIdx.x, t = threadIdx.x;
  __shared__ u16 tile[64][65];
  if (bid < 256) {
    const float* src;
    u16* dst;
    int base;
    if (bid < 192) { src = wqkv; dst = WQ; base = bid * 1024; }
    else           { src = wout; dst = WO; base = (bid - 192) * 1024; }
    float4 v = *(const float4*)(src + base + t * 4);
    uint2 pk = make_uint2((uint)f2bf(v.x) | ((uint)f2bf(v.y) << 16),
                          (uint)f2bf(v.z) | ((uint)f2bf(v.w) << 16));
    *(uint2*)(dst + base + t * 4) = pk;
    return;
  }
  const int id = bid - 256;
  const int pt = id & 15, ct = (id >> 4) & 3, b = id >> 6;
  {
    const int px = t & 63, cq = t >> 6;
    const float* xb = x + ((size_t)(b * C + ct * 64)) * NPIX + pt * 64;
#pragma unroll
    for (int m = 0; m < 16; ++m) {
      const int c = cq * 16 + m;
      tile[c][px] = f2bf(xb[(size_t)c * NPIX + px]);
    }
  }
  __syncthreads();
  {
    const int cc = t & 63, pq = t >> 6;
    const int c = ct * 64 + cc;
    const int kc = c >> 5, quad = (c >> 3) & 3, mm = c & 7;
    u16* dst = XT + ((size_t)((b * 64 + pt * 4 + pq) * 8 + kc) * 512 +
                     quad * 128 + mm);
#pragma unroll
    for (int m = 0; m < 16; ++m)
      dst[m * 8] = tile[cc][pq * 16 + m];
  }
}

// ---------------------------------------------------------------------------
// K1: QKV GEMM via MFMA, XTF fragment-order B loads (1KB bursts).
// Q pre-scaled by SCALE*LOG2E, row-major (k_red diag compensates).
// K and V stored in FRAGMENT-ORDER layouts (contiguous 4KB per 64-j tile):
//   KF[bh][ (j>>4)*512 + ((d>>3)*16 + (j&15))*8 + (d&7) ]         = K[j][d]
//   VF[bh][ ((j>>4)*2 + (d>>4))*256 + (((j>>2)&3)*16 + (d&15))*4 + (j&3) ]
// ---------------------------------------------------------------------------
__global__ __launch_bounds__(256) void k_qkv_mfma(
    const u16* __restrict__ XTF, const u16* __restrict__ WQ,
    u16* __restrict__ Q, u16* __restrict__ Kk, u16* __restrict__ VT) {
  const int ob = blockIdx.x, pb = blockIdx.y, b = blockIdx.z;
  const int wv = threadIdx.x >> 6, lane = threadIdx.x & 63;
  const int quad = lane >> 4, l15 = lane & 15;
  const int part = ob >> 2;
  const int odl = (ob & 3) * 64 + wv * 16;
  const int hh = odl >> 5, d0 = odl & 31;
  const int bh = b * HEADS + hh;
  const int pix0 = pb * 128;

  const u16* arow = WQ + (size_t)(ob * 64 + wv * 16 + l15) * C;
  bf16x8 af[8];
#pragma unroll
  for (int kc = 0; kc < 8; ++kc)
    af[kc] = *(const bf16x8*)(arow + kc * 32 + quad * 8);

  const u16* xb = XTF + (size_t)(b * 64 + pb * 8) * 8 * 512 + lane * 8;
  f32x4 acc[8];
#pragma unroll
  for (int nt = 0; nt < 8; ++nt) acc[nt] = (f32x4){0.f, 0.f, 0.f, 0.f};

  for (int kc = 0; kc < 8; ++kc) {
#pragma unroll
    for (int nt = 0; nt < 8; ++nt) {
      bf16x8 bfr = *(const bf16x8*)(xb + (size_t)(nt * 8 + kc) * 512);
      acc[nt] = __builtin_amdgcn_mfma_f32_16x16x32_bf16(af[kc], bfr, acc[nt], 0, 0, 0);
    }
  }

  if (part == 0) {
    const float qs = SCALE * LOG2E;
    u16* dst = Q + (size_t)bh * NPIX * D;
#pragma unroll
    for (int nt = 0; nt < 8; ++nt) {
      const int pix = pix0 + nt * 16 + l15;
      uint2 pk = make_uint2(
          (uint)f2bf(acc[nt][0] * qs) | ((uint)f2bf(acc[nt][1] * qs) << 16),
          (uint)f2bf(acc[nt][2] * qs) | ((uint)f2bf(acc[nt][3] * qs) << 16));
      *(uint2*)(dst + (size_t)pix * D + d0 + 4 * quad) = pk;
    }
  } else if (part == 1) {
    // KF fragment-order: rows o = d0+4*quad+r, r=0..3 land in one uint2
    u16* kfb = Kk + (size_t)bh * NPIX * D;
    const int lane_k8 = (((d0 >> 3) + (quad >> 1)) * 16 + l15) * 8 + (quad & 1) * 4;
#pragma unroll
    for (int nt = 0; nt < 8; ++nt) {
      uint2 pk = make_uint2(
          (uint)f2bf(acc[nt][0]) | ((uint)f2bf(acc[nt][1]) << 16),
          (uint)f2bf(acc[nt][2]) | ((uint)f2bf(acc[nt][3]) << 16));
      *(uint2*)(kfb + (size_t)(pb * 8 + nt) * 512 + lane_k8) = pk;
    }
  } else {
    u16* vb = VT + (size_t)bh * NPIX * D;
#pragma unroll
    for (int nt = 0; nt < 8; ++nt) {
      const int pix = pix0 + nt * 16 + l15;           // j
      const int jb16 = pix >> 4, qa = (pix >> 2) & 3, m = pix & 3;
#pragma unroll
      for (int r = 0; r < 4; ++r) {
        const int d = d0 + 4 * quad + r;              // 0..31
        const int nta = d >> 4, l15a = d & 15;
        vb[((size_t)(jb16 * 2 + nta) * 64 + qa * 16 + l15a) * 4 + m] =
            f2bf(acc[nt][r]);
      }
    }
  }
}

// ---------------------------------------------------------------------------
// R: fused reductions. Blocks [0,8): diag_vec[b] (Q carries SCALE*LOG2E, so
// final factor is 0.125/LOG2E; K read via KF layout). Blocks [8,72):
// colsum[bh] over the VF layout.
// ---------------------------------------------------------------------------
__global__ __launch_bounds__(256) void k_red(
    const u16* __restrict__ Q, const u16* __restrict__ KF,
    const u16* __restrict__ VT, float* __restrict__ diagv,
    float* __restrict__ colsum) {
  const int bid = blockIdx.x, tid = threadIdx.x;
  __shared__ float red[256];
  if (bid < 8) {
    const int b = bid;
    const int hh = tid >> 5, dd = tid & 31;
    const u16* qb = Q + (size_t)(b * HEADS + hh) * NPIX * D;
    const u16* kb = KF + (size_t)(b * HEADS + hh) * NPIX * D;
    float s = 0.f;
#pragma unroll 4
    for (int t = 0; t < 32; ++t) {
      const int j = t * 33;
      float qv = bfval(qb[(size_t)j * D + dd]);
      float kv = bfval(kb[(size_t)(j >> 4) * 512 +
                          ((dd >> 3) * 16 + (j & 15)) * 8 + (dd & 7)]);
      s += qv * kv;
    }
    red[tid] = s;
    __syncthreads();
    if (tid < 32) {
      float v = 0.f;
#pragma unroll
      for (int h8 = 0; h8 < 8; ++h8) v += red[h8 * 32 + tid];
      diagv[b * 32 + tid] = v * (0.125f / LOG2E);
    }
  } else {
    const int bh = bid - 8;
    const int d = tid >> 3, sl = tid & 7;
    const int nta = d >> 4, l15a = d & 15;
    const u16* vb = VT + (size_t)bh * NPIX * D;
    float s = 0.f;
    for (int jb = 0; jb < 8; ++jb) {
      const int jb16 = sl * 8 + jb;
#pragma unroll
      for (int qa = 0; qa < 4; ++qa) {
        const uint2 u = *(const uint2*)(
            vb + ((size_t)(jb16 * 2 + nta) * 64 + qa * 16 + l15a) * 4);
        s += bf_lo(u.x) + bf_hi(u.x) + bf_lo(u.y) + bf_hi(u.y);
      }
    }
    red[tid] = s;
    __syncthreads();
    if (tid < 32) {
      float v = 0.f;
#pragma unroll
      for (int g = 0; g < 8; ++g) v += red[tid * 8 + g];
      colsum[bh * D + tid] = v;
    }
  }
}

// ---------------------------------------------------------------------------
// K2: MFMA flash attention, 8-wave blocks sharing double-buffered LDS K/V.
// Grid (8 qchunks of 128, 64 bh), 512 thr: wave wv owns q-rows
// i0 = qc*128 + wv*16. All 8 waves consume IDENTICAL K/V tiles; each wave
// stages 1KB/iter (1 coalesced 16B/lane load -> 1 ds_write_b128). Halves
// K/V global traffic vs 1024-block version and halves staging work.
// S^T via mfma16x16x32(K,Q); PV via mfma_f32_16x16x16bf16_1k.
// ---------------------------------------------------------------------------
__global__ __launch_bounds__(512, 4) void k_attn(
    const u16* __restrict__ Q, const u16* __restrict__ KF,
    const u16* __restrict__ VF, const float* __restrict__ diagv,
    const float* __restrict__ colsum, u16* __restrict__ AOT) {
  const int qc = blockIdx.x;           // 0..7
  const int bh = blockIdx.y;           // 0..63
  const int b = bh >> 3, hh = bh & 7;
  const int wv = threadIdx.x >> 6, lane = threadIdx.x & 63;
  const int quad = lane >> 4, l15 = lane & 15;
  const int i0 = qc * 128 + wv * 16;

  __shared__ u16 sbuf[2][4096];        // 2 x 8KB: [K 4KB | V 4KB]

  const u16* Qb  = Q  + (size_t)bh * NPIX * D;
  const u16* KFb = KF + (size_t)bh * NPIX * D;
  const u16* VFb = VF + (size_t)bh * NPIX * D;

  bf16x8 qfrag = *(const bf16x8*)(Qb + (size_t)(i0 + l15) * D + quad * 8);

  f32x4 oacc[2];
  oacc[0] = (f32x4){0.f, 0.f, 0.f, 0.f};
  oacc[1] = (f32x4){0.f, 0.f, 0.f, 0.f};
  float lacc[4] = {};

  // staging role: waves 0-3 copy the K tile quarters, waves 4-7 the V tile
  const int soff = (wv >= 4 ? 2048 : 0) + (wv & 3) * 512 + lane * 8;
  const u16* gsrc = (wv < 4 ? KFb : VFb) + (wv & 3) * 512 + lane * 8;
  u16* ldst[2] = { &sbuf[0][soff], &sbuf[1][soff] };

  // prologue: stage tile 0 into buffer 0
  *(uint4*)(ldst[0]) = *(const uint4*)(gsrc);
  __syncthreads();

  int cur = 0;
  for (int it = 0; it < 16; ++it) {
    // prefetch next tile into the other buffer (hidden under compute)
    if (it < 15)
      *(uint4*)(ldst[cur ^ 1]) = *(const uint4*)(gsrc + (size_t)(it + 1) * 2048);
    const u16* sK = &sbuf[cur][0];
    const u16* sV = &sbuf[cur][2048];

    // S^T = K Q^T: lane holds P^T rows j = jt*16+quad*4+r, col i = l15
    f32x4 st[4];
#pragma unroll
    for (int jt = 0; jt < 4; ++jt) {
      bf16x8 kfrag = *(const bf16x8*)(sK + jt * 512 + lane * 8);
      st[jt] = __builtin_amdgcn_mfma_f32_16x16x32_bf16(
          kfrag, qfrag, (f32x4){0.f, 0.f, 0.f, 0.f}, 0, 0, 0);
    }

    // exp (arg pre-scaled by SCALE*LOG2E at QKV time) + row-sum accumulate
#pragma unroll
    for (int jt = 0; jt < 4; ++jt)
#pragma unroll
      for (int r = 0; r < 4; ++r) {
        float pv = exp2f(fminf(st[jt][r], 80.f));
        lacc[r] += pv;
        st[jt][r] = pv;
      }

    // pack P in-register (A-frag of K=16 MFMA) + PV, no cross-lane movement
    __builtin_amdgcn_s_setprio(1);
#pragma unroll
    for (int jt = 0; jt < 4; ++jt) {
      union { uint u[2]; bf16x4 v; } pa;
      pa.u[0] = pk2(st[jt][0], st[jt][1]);
      pa.u[1] = pk2(st[jt][2], st[jt][3]);
#pragma unroll
      for (int nt = 0; nt < 2; ++nt) {
        bf16x4 vfr = *(const bf16x4*)(sV + (jt * 2 + nt) * 256 + lane * 4);
        oacc[nt] = __builtin_amdgcn_mfma_f32_16x16x16bf16_1k(
            pa.v, vfr, oacc[nt], 0, 0, 0);
      }
    }
    __builtin_amdgcn_s_setprio(0);

    __syncthreads();   // staged writes visible; all waves done with cur
    cur ^= 1;
  }

  // row-sum: lane already has 16 j-classes for its row; reduce across quads
  float lt = (lacc[0] + lacc[1]) + (lacc[2] + lacc[3]);
  lt += __shfl_xor(lt, 16, 64);
  lt += __shfl_xor(lt, 32, 64);
  const float linv = 1.f / lt;
  // oacc rows are i = quad*4+r; fetch 1/l from lane l15 = quad*4+r
  float rinv[4];
#pragma unroll
  for (int r = 0; r < 4; ++r) rinv[r] = __shfl(linv, quad * 4 + r, 64);

  // epilogue: normalize, diag term (rows < 32), store AOT[b][pix][ch]
  const bool do_diag = (i0 < 32);
#pragma unroll
  for (int nt = 0; nt < 2; ++nt) {
    const int dch = hh * 32 + nt * 16 + l15;
    float cs = do_diag ? colsum[bh * D + (nt * 16 + l15)] : 0.f;
#pragma unroll
    for (int r = 0; r < 4; ++r) {
      const int irow = i0 + quad * 4 + r;
      float o = oacc[nt][r] * rinv[r];
      if (do_diag) o += 0.3f * diagv[b * 32 + irow] * cs;
      AOT[((size_t)b * NPIX + irow) * C + dch] = f2bf(o);
    }
  }
}

// ---------------------------------------------------------------------------
// K3: gate. One block per (b, row h); 16 distinct gate values per row.
// ---------------------------------------------------------------------------
__global__ __launch_bounds__(256) void k_gate(
    const float* __restrict__ x,
    const float* __restrict__ wg1, const float* __restrict__ bg1,
    const float* __restrict__ wg2, const float* __restrict__ bg2,
    float* __restrict__ gate) {
  const int h = blockIdx.x, b = blockIdx.y, tid = threadIdx.x;
  __shared__ float pl[16 * 257];
  __shared__ float gl[16 * 65];

  {
    const int c = tid;
    const float* row = x + ((size_t)(b * C + c) * NPIX + h * 32);
    float v[32];
#pragma unroll
    for (int m = 0; m < 32; ++m) v[m] = row[m];
#pragma unroll
    for (int k = 0; k < 16; ++k) pl[k * 257 + c] = fabsf(v[k] - v[31 - k]);
  }
  __syncthreads();

  const int o16 = tid >> 4, k = tid & 15;
#pragma unroll 1
  for (int p = 0; p < 4; ++p) {
    const int o = p * 16 + o16;
    const float* wr = wg1 + o * C;
    float a0 = 0.f, a1 = 0.f, a2 = 0.f, a3 = 0.f;
#pragma unroll 4
    for (int c = 0; c < C; c += 4) {
      a0 += wr[c]     * pl[k * 257 + c];
      a1 += wr[c + 1] * pl[k * 257 + c + 1];
      a2 += wr[c + 2] * pl[k * 257 + c + 2];
      a3 += wr[c + 3] * pl[k * 257 + c + 3];
    }
    float a = bg1[o] + ((a0 + a1) + (a2 + a3));
    gl[k * 65 + o] = 0.5f * a * (1.f + erff(a * 0.70710678118654752f));
  }
  __syncthreads();

  if (tid < 16) {
    float s = bg2[0];
    for (int o = 0; o < 64; ++o)
      s += wg2[o] * gl[tid * 65 + o];
    gate[(b * 32 + h) * 16 + tid] = 1.f / (1.f + expf(-s));
  }
}

// ---------------------------------------------------------------------------
// K4: output GEMM via MFMA, gate+bias fused. out fp32 [b][o][pix].
// ---------------------------------------------------------------------------
__global__ __launch_bounds__(256) void k_out_mfma(
    const u16* __restrict__ AOT, const u16* __restrict__ WO,
    const float* __restrict__ bout, const float* __restrict__ gate,
    float* __restrict__ out) {
  const int ob = blockIdx.x, pb = blockIdx.y, b = blockIdx.z;
  const int wv = threadIdx.x >> 6, lane = threadIdx.x & 63;
  const int quad = lane >> 4, l15 = lane & 15;
  const int o0 = ob * 64 + wv * 16;
  const int pix0 = pb * 128;

  const u16* arow = WO + (size_t)(o0 + l15) * C;
  bf16x8 af[8];
#pragma unroll
  for (int kc = 0; kc < 8; ++kc)
    af[kc] = *(const bf16x8*)(arow + kc * 32 + quad * 8);

  const u16* ab = AOT + (size_t)(b * NPIX + pix0) * C;
  f32x4 acc[8];
#pragma unroll
  for (int nt = 0; nt < 8; ++nt) acc[nt] = (f32x4){0.f, 0.f, 0.f, 0.f};

  for (int kc = 0; kc < 8; ++kc) {
#pragma unroll
    for (int nt = 0; nt < 8; ++nt) {
      bf16x8 bfr = *(const bf16x8*)(ab + (size_t)(nt * 16 + l15) * C +
                                    kc * 32 + quad * 8);
      acc[nt] = __builtin_amdgcn_mfma_f32_16x16x32_bf16(af[kc], bfr, acc[nt], 0, 0, 0);
    }
  }

#pragma unroll
  for (int nt = 0; nt < 8; ++nt) {
    const int pix = pix0 + nt * 16 + l15;
    const float gf = 1.f + gate[(b * 32 + (pix >> 5)) * 16 + ((pix & 31) >> 1)];
#pragma unroll
    for (int r = 0; r < 4; ++r) {
      const int o = o0 + 4 * quad + r;
      out[((size_t)b * C + o) * NPIX + pix] = acc[nt][r] * gf + bout[o];
    }
  }
}

// ---------------------------------------------------------------------------
extern "C" void kernel_launch(void* const* d_in, const int* in_sizes, int n_in,
                              void* d_out, int out_size, void* d_ws, size_t ws_size,
                              hipStream_t stream) {
  const float* x    = (const float*)d_in[0];
  const float* wqkv = (const float*)d_in[1];
  const float* wout = (const float*)d_in[2];
  const float* bout = (const float*)d_in[3];
  const float* wg1  = (const float*)d_in[4];
  const float* bg1  = (const float*)d_in[5];
  const float* wg2  = (const float*)d_in[6];
  const float* bg2  = (const float*)d_in[7];
  float* out = (float*)d_out;

  const size_t SZ = (size_t)B * HEADS * NPIX * D;   // 2,097,152
  u16* XT = (u16*)d_ws;
  u16* WQ = XT + SZ;
  u16* WO = WQ + (size_t)OC * C;
  u16* Q  = WO + (size_t)C * C;
  u16* Kq = Q + SZ;
  u16* VT = Kq + SZ;
  float* DIAG = (float*)(VT + SZ);
  float* COL  = DIAG + 256;
  float* GATE = COL + 2048;
  u16* AOT = XT;   // alias: XT dead after k_qkv_mfma

  hipLaunchKernelGGL(k_prep, dim3(768), dim3(256), 0, stream,
                     x, wqkv, wout, WQ, WO, XT);
  hipLaunchKernelGGL(k_qkv_mfma, dim3(12, 8, B), dim3(256), 0, stream,
                     XT, WQ, Q, Kq, VT);
  hipLaunchKernelGGL(k_red, dim3(72), dim3(256), 0, stream,
                     Q, Kq, VT, DIAG, COL);
  hipLaunchKernelGGL(k_attn, dim3(8, 64), dim3(512), 0, stream,
                     Q, Kq, VT, DIAG, COL, AOT);
  hipLaunchKernelGGL(k_gate, dim3(32, B), dim3(256), 0, stream,
                     x, wg1, bg1, wg2, bg2, GATE);
  hipLaunchKernelGGL(k_out_mfma, dim3(4, 8, B), dim3(256), 0, stream,
                     AOT, WO, bout, GATE, out);
}

// Round 10
// 147.800 us; speedup vs baseline: 1.1993x; 1.0581x over previous
//
#include <hip/hip_runtime.h>
#include <hip/hip_bf16.h>
#include <math.h>

#define B 8
#define C 256
#define HEADS 8
#define D 32
#define NPIX 1024
#define OC 768
#define SCALE 0.17677669529663687f   // 1/sqrt(32)
#define LOG2E 1.4426950408889634f

typedef unsigned int uint;
typedef unsigned short u16;
typedef __attribute__((ext_vector_type(8))) short bf16x8;
typedef __attribute__((ext_vector_type(4))) short bf16x4;
typedef __attribute__((ext_vector_type(4))) float f32x4;

static __device__ inline u16 f2bf(float f) {   // RNE f32->bf16
  uint u = __float_as_uint(f);
  return (u16)((u + 0x7fffu + ((u >> 16) & 1u)) >> 16);
}
static __device__ inline float bfval(u16 v) { return __uint_as_float((uint)v << 16); }
static __device__ inline float bf_lo(uint u) { return __uint_as_float(u << 16); }
static __device__ inline float bf_hi(uint u) { return __uint_as_float(u & 0xffff0000u); }

// packed f32x2 -> bf16x2 (lowers to v_cvt_pk_bf16_f32 on gfx950)
static __device__ inline uint pk2(float lo, float hi) {
  union { __hip_bfloat162 h; uint u; } cv;
  cv.h = __float22bfloat162_rn(float2{lo, hi});
  return cv.u;
}

// ---------------------------------------------------------------------------
// P0: fused prep + gate. Blocks [0,256): weights fp32->bf16.
// Blocks [256,768): transpose-convert x -> FRAGMENT-ORDER XTF:
//   XTF[((b*64 + p16)*8 + kc)*512 + (quad*16 + l15)*8 + mm]
//     = x_bf16[pix = p16*16 + l15][c = kc*32 + quad*8 + mm]
// Blocks [768,1024): gate MLP (depends only on x) — overlaps with prep.
// ---------------------------------------------------------------------------
__global__ __launch_bounds__(256) void k_prep_gate(
    const float* __restrict__ x, const float* __restrict__ wqkv,
    const float* __restrict__ wout,
    const float* __restrict__ wg1, const float* __restrict__ bg1,
    const float* __restrict__ wg2, const float* __restrict__ bg2,
    u16* __restrict__ WQ, u16* __restrict__ WO, u16* __restrict__ XT,
    float* __restrict__ gate) {
  const int bid = blockIdx.x, t = threadIdx.x;
  __shared__ float smem[16 * 257 + 16 * 65];   // 20.6 KB, union across roles
  if (bid < 256) {
    const float* src;
    u16* dst;
    int base;
    if (bid < 192) { src = wqkv; dst = WQ; base = bid * 1024; }
    else           { src = wout; dst = WO; base = (bid - 192) * 1024; }
    float4 v = *(const float4*)(src + base + t * 4);
    uint2 pk = make_uint2((uint)f2bf(v.x) | ((uint)f2bf(v.y) << 16),
                          (uint)f2bf(v.z) | ((uint)f2bf(v.w) << 16));
    *(uint2*)(dst + base + t * 4) = pk;
    return;
  }
  if (bid < 768) {
    u16 (*tile)[65] = (u16(*)[65])smem;
    const int id = bid - 256;
    const int pt = id & 15, ct = (id >> 4) & 3, b = id >> 6;
    {
      const int px = t & 63, cq = t >> 6;
      const float* xb = x + ((size_t)(b * C + ct * 64)) * NPIX + pt * 64;
#pragma unroll
      for (int m = 0; m < 16; ++m) {
        const int c = cq * 16 + m;
        tile[c][px] = f2bf(xb[(size_t)c * NPIX + px]);
      }
    }
    __syncthreads();
    {
      const int cc = t & 63, pq = t >> 6;
      const int c = ct * 64 + cc;
      const int kc = c >> 5, quad = (c >> 3) & 3, mm = c & 7;
      u16* dst = XT + ((size_t)((b * 64 + pt * 4 + pq) * 8 + kc) * 512 +
                       quad * 128 + mm);
#pragma unroll
      for (int m = 0; m < 16; ++m)
        dst[m * 8] = tile[cc][pq * 16 + m];
    }
    return;
  }
  // ---- gate role ----
  const int id = bid - 768;
  const int h = id & 31, b = id >> 5;
  float* pl = smem;                // [16][257]
  float* gl = smem + 16 * 257;     // [16][65]
  {
    const int c = t;
    const float* row = x + ((size_t)(b * C + c) * NPIX + h * 32);
    float v[32];
#pragma unroll
    for (int m = 0; m < 32; ++m) v[m] = row[m];
#pragma unroll
    for (int k = 0; k < 16; ++k) pl[k * 257 + c] = fabsf(v[k] - v[31 - k]);
  }
  __syncthreads();

  const int o16 = t >> 4, k = t & 15;
#pragma unroll 1
  for (int p = 0; p < 4; ++p) {
    const int o = p * 16 + o16;
    const float* wr = wg1 + o * C;
    float a0 = 0.f, a1 = 0.f, a2 = 0.f, a3 = 0.f;
#pragma unroll 4
    for (int c = 0; c < C; c += 4) {
      a0 += wr[c]     * pl[k * 257 + c];
      a1 += wr[c + 1] * pl[k * 257 + c + 1];
      a2 += wr[c + 2] * pl[k * 257 + c + 2];
      a3 += wr[c + 3] * pl[k * 257 + c + 3];
    }
    float a = bg1[o] + ((a0 + a1) + (a2 + a3));
    gl[k * 65 + o] = 0.5f * a * (1.f + erff(a * 0.70710678118654752f));
  }
  __syncthreads();

  if (t < 16) {
    float s = bg2[0];
    for (int o = 0; o < 64; ++o)
      s += wg2[o] * gl[t * 65 + o];
    gate[(b * 32 + h) * 16 + t] = 1.f / (1.f + expf(-s));
  }
}

// ---------------------------------------------------------------------------
// K1: QKV GEMM via MFMA, XTF fragment-order B loads (1KB bursts).
// Q pre-scaled by SCALE*LOG2E, row-major (k_red diag compensates).
// K and V stored in FRAGMENT-ORDER layouts (contiguous 4KB per 64-j tile):
//   KF[bh][ (j>>4)*512 + ((d>>3)*16 + (j&15))*8 + (d&7) ]         = K[j][d]
//   VF[bh][ ((j>>4)*2 + (d>>4))*256 + (((j>>2)&3)*16 + (d&15))*4 + (j&3) ]
// ---------------------------------------------------------------------------
__global__ __launch_bounds__(256) void k_qkv_mfma(
    const u16* __restrict__ XTF, const u16* __restrict__ WQ,
    u16* __restrict__ Q, u16* __restrict__ Kk, u16* __restrict__ VT) {
  const int ob = blockIdx.x, pb = blockIdx.y, b = blockIdx.z;
  const int wv = threadIdx.x >> 6, lane = threadIdx.x & 63;
  const int quad = lane >> 4, l15 = lane & 15;
  const int part = ob >> 2;
  const int odl = (ob & 3) * 64 + wv * 16;
  const int hh = odl >> 5, d0 = odl & 31;
  const int bh = b * HEADS + hh;
  const int pix0 = pb * 128;

  const u16* arow = WQ + (size_t)(ob * 64 + wv * 16 + l15) * C;
  bf16x8 af[8];
#pragma unroll
  for (int kc = 0; kc < 8; ++kc)
    af[kc] = *(const bf16x8*)(arow + kc * 32 + quad * 8);

  const u16* xb = XTF + (size_t)(b * 64 + pb * 8) * 8 * 512 + lane * 8;
  f32x4 acc[8];
#pragma unroll
  for (int nt = 0; nt < 8; ++nt) acc[nt] = (f32x4){0.f, 0.f, 0.f, 0.f};

  for (int kc = 0; kc < 8; ++kc) {
#pragma unroll
    for (int nt = 0; nt < 8; ++nt) {
      bf16x8 bfr = *(const bf16x8*)(xb + (size_t)(nt * 8 + kc) * 512);
      acc[nt] = __builtin_amdgcn_mfma_f32_16x16x32_bf16(af[kc], bfr, acc[nt], 0, 0, 0);
    }
  }

  if (part == 0) {
    const float qs = SCALE * LOG2E;
    u16* dst = Q + (size_t)bh * NPIX * D;
#pragma unroll
    for (int nt = 0; nt < 8; ++nt) {
      const int pix = pix0 + nt * 16 + l15;
      uint2 pk = make_uint2(
          (uint)f2bf(acc[nt][0] * qs) | ((uint)f2bf(acc[nt][1] * qs) << 16),
          (uint)f2bf(acc[nt][2] * qs) | ((uint)f2bf(acc[nt][3] * qs) << 16));
      *(uint2*)(dst + (size_t)pix * D + d0 + 4 * quad) = pk;
    }
  } else if (part == 1) {
    // KF fragment-order: rows o = d0+4*quad+r, r=0..3 land in one uint2
    u16* kfb = Kk + (size_t)bh * NPIX * D;
    const int lane_k8 = (((d0 >> 3) + (quad >> 1)) * 16 + l15) * 8 + (quad & 1) * 4;
#pragma unroll
    for (int nt = 0; nt < 8; ++nt) {
      uint2 pk = make_uint2(
          (uint)f2bf(acc[nt][0]) | ((uint)f2bf(acc[nt][1]) << 16),
          (uint)f2bf(acc[nt][2]) | ((uint)f2bf(acc[nt][3]) << 16));
      *(uint2*)(kfb + (size_t)(pb * 8 + nt) * 512 + lane_k8) = pk;
    }
  } else {
    u16* vb = VT + (size_t)bh * NPIX * D;
#pragma unroll
    for (int nt = 0; nt < 8; ++nt) {
      const int pix = pix0 + nt * 16 + l15;           // j
      const int jb16 = pix >> 4, qa = (pix >> 2) & 3, m = pix & 3;
#pragma unroll
      for (int r = 0; r < 4; ++r) {
        const int d = d0 + 4 * quad + r;              // 0..31
        const int nta = d >> 4, l15a = d & 15;
        vb[((size_t)(jb16 * 2 + nta) * 64 + qa * 16 + l15a) * 4 + m] =
            f2bf(acc[nt][r]);
      }
    }
  }
}

// ---------------------------------------------------------------------------
// R: fused reductions. Blocks [0,8): diag_vec[b] (Q carries SCALE*LOG2E, so
// final factor is 0.125/LOG2E; K read via KF layout). Blocks [8,72):
// colsum[bh] over the VF layout.
// ---------------------------------------------------------------------------
__global__ __launch_bounds__(256) void k_red(
    const u16* __restrict__ Q, const u16* __restrict__ KF,
    const u16* __restrict__ VT, float* __restrict__ diagv,
    float* __restrict__ colsum) {
  const int bid = blockIdx.x, tid = threadIdx.x;
  __shared__ float red[256];
  if (bid < 8) {
    const int b = bid;
    const int hh = tid >> 5, dd = tid & 31;
    const u16* qb = Q + (size_t)(b * HEADS + hh) * NPIX * D;
    const u16* kb = KF + (size_t)(b * HEADS + hh) * NPIX * D;
    float s = 0.f;
#pragma unroll 4
    for (int t = 0; t < 32; ++t) {
      const int j = t * 33;
      float qv = bfval(qb[(size_t)j * D + dd]);
      float kv = bfval(kb[(size_t)(j >> 4) * 512 +
                          ((dd >> 3) * 16 + (j & 15)) * 8 + (dd & 7)]);
      s += qv * kv;
    }
    red[tid] = s;
    __syncthreads();
    if (tid < 32) {
      float v = 0.f;
#pragma unroll
      for (int h8 = 0; h8 < 8; ++h8) v += red[h8 * 32 + tid];
      diagv[b * 32 + tid] = v * (0.125f / LOG2E);
    }
  } else {
    const int bh = bid - 8;
    const int d = tid >> 3, sl = tid & 7;
    const int nta = d >> 4, l15a = d & 15;
    const u16* vb = VT + (size_t)bh * NPIX * D;
    float s = 0.f;
    for (int jb = 0; jb < 8; ++jb) {
      const int jb16 = sl * 8 + jb;
#pragma unroll
      for (int qa = 0; qa < 4; ++qa) {
        const uint2 u = *(const uint2*)(
            vb + ((size_t)(jb16 * 2 + nta) * 64 + qa * 16 + l15a) * 4);
        s += bf_lo(u.x) + bf_hi(u.x) + bf_lo(u.y) + bf_hi(u.y);
      }
    }
    red[tid] = s;
    __syncthreads();
    if (tid < 32) {
      float v = 0.f;
#pragma unroll
      for (int g = 0; g < 8; ++g) v += red[tid * 8 + g];
      colsum[bh * D + tid] = v;
    }
  }
}

// ---------------------------------------------------------------------------
// K2: MFMA flash attention, 8-wave blocks sharing double-buffered LDS K/V.
// Grid (8 qchunks of 128, 64 bh), 512 thr. Epilogue stores the attention
// output in FRAGMENT-ORDER AOF (XTF-style) so k_out's B-fragment loads
// are contiguous 1KB bursts:
//   AOF[((b*64 + p16)*8 + hh)*512 + (qa*16 + lr)*8 + mm]
//     = A[pix = p16*16 + lr][ch = hh*32 + qa*8 + mm]
// ---------------------------------------------------------------------------
__global__ __launch_bounds__(512, 4) void k_attn(
    const u16* __restrict__ Q, const u16* __restrict__ KF,
    const u16* __restrict__ VF, const float* __restrict__ diagv,
    const float* __restrict__ colsum, u16* __restrict__ AOT) {
  const int qc = blockIdx.x;           // 0..7
  const int bh = blockIdx.y;           // 0..63
  const int b = bh >> 3, hh = bh & 7;
  const int wv = threadIdx.x >> 6, lane = threadIdx.x & 63;
  const int quad = lane >> 4, l15 = lane & 15;
  const int i0 = qc * 128 + wv * 16;

  __shared__ u16 sbuf[2][4096];        // 2 x 8KB: [K 4KB | V 4KB]

  const u16* Qb  = Q  + (size_t)bh * NPIX * D;
  const u16* KFb = KF + (size_t)bh * NPIX * D;
  const u16* VFb = VF + (size_t)bh * NPIX * D;

  bf16x8 qfrag = *(const bf16x8*)(Qb + (size_t)(i0 + l15) * D + quad * 8);

  f32x4 oacc[2];
  oacc[0] = (f32x4){0.f, 0.f, 0.f, 0.f};
  oacc[1] = (f32x4){0.f, 0.f, 0.f, 0.f};
  float lacc[4] = {};

  // staging role: waves 0-3 copy the K tile quarters, waves 4-7 the V tile
  const int soff = (wv >= 4 ? 2048 : 0) + (wv & 3) * 512 + lane * 8;
  const u16* gsrc = (wv < 4 ? KFb : VFb) + (wv & 3) * 512 + lane * 8;
  u16* ldst[2] = { &sbuf[0][soff], &sbuf[1][soff] };

  // prologue: stage tile 0 into buffer 0
  *(uint4*)(ldst[0]) = *(const uint4*)(gsrc);
  __syncthreads();

  int cur = 0;
  for (int it = 0; it < 16; ++it) {
    // prefetch next tile into the other buffer (hidden under compute)
    if (it < 15)
      *(uint4*)(ldst[cur ^ 1]) = *(const uint4*)(gsrc + (size_t)(it + 1) * 2048);
    const u16* sK = &sbuf[cur][0];
    const u16* sV = &sbuf[cur][2048];

    // S^T = K Q^T: lane holds P^T rows j = jt*16+quad*4+r, col i = l15
    f32x4 st[4];
#pragma unroll
    for (int jt = 0; jt < 4; ++jt) {
      bf16x8 kfrag = *(const bf16x8*)(sK + jt * 512 + lane * 8);
      st[jt] = __builtin_amdgcn_mfma_f32_16x16x32_bf16(
          kfrag, qfrag, (f32x4){0.f, 0.f, 0.f, 0.f}, 0, 0, 0);
    }

    // exp (arg pre-scaled by SCALE*LOG2E at QKV time) + row-sum accumulate
#pragma unroll
    for (int jt = 0; jt < 4; ++jt)
#pragma unroll
      for (int r = 0; r < 4; ++r) {
        float pv = exp2f(fminf(st[jt][r], 80.f));
        lacc[r] += pv;
        st[jt][r] = pv;
      }

    // pack P in-register (A-frag of K=16 MFMA) + PV, no cross-lane movement
    __builtin_amdgcn_s_setprio(1);
#pragma unroll
    for (int jt = 0; jt < 4; ++jt) {
      union { uint u[2]; bf16x4 v; } pa;
      pa.u[0] = pk2(st[jt][0], st[jt][1]);
      pa.u[1] = pk2(st[jt][2], st[jt][3]);
#pragma unroll
      for (int nt = 0; nt < 2; ++nt) {
        bf16x4 vfr = *(const bf16x4*)(sV + (jt * 2 + nt) * 256 + lane * 4);
        oacc[nt] = __builtin_amdgcn_mfma_f32_16x16x16bf16_1k(
            pa.v, vfr, oacc[nt], 0, 0, 0);
      }
    }
    __builtin_amdgcn_s_setprio(0);

    __syncthreads();   // staged writes visible; all waves done with cur
    cur ^= 1;
  }

  // row-sum: lane already has 16 j-classes for its row; reduce across quads
  float lt = (lacc[0] + lacc[1]) + (lacc[2] + lacc[3]);
  lt += __shfl_xor(lt, 16, 64);
  lt += __shfl_xor(lt, 32, 64);
  const float linv = 1.f / lt;
  // oacc rows are i = quad*4+r; fetch 1/l from lane l15 = quad*4+r
  float rinv[4];
#pragma unroll
  for (int r = 0; r < 4; ++r) rinv[r] = __shfl(linv, quad * 4 + r, 64);

  // epilogue: normalize, diag term (rows < 32), store AOF fragment-order
  const bool do_diag = (i0 < 32);
  const int p16 = i0 >> 4;
  u16* aobase = AOT + ((size_t)(b * 64 + p16) * 8 + hh) * 512 + (l15 & 7);
  const int hi8 = l15 >> 3;
#pragma unroll
  for (int nt = 0; nt < 2; ++nt) {
    const int qa = nt * 2 + hi8;     // ch = hh*32 + qa*8 + (l15&7) = hh*32+nt*16+l15
    float cs = do_diag ? colsum[bh * D + (nt * 16 + l15)] : 0.f;
#pragma unroll
    for (int r = 0; r < 4; ++r) {
      const int irow = i0 + quad * 4 + r;
      float o = oacc[nt][r] * rinv[r];
      if (do_diag) o += 0.3f * diagv[b * 32 + irow] * cs;
      aobase[(qa * 16 + quad * 4 + r) * 8] = f2bf(o);
    }
  }
}

// ---------------------------------------------------------------------------
// K4: output GEMM via MFMA, AOF fragment-order B loads (1KB bursts),
// gate+bias fused. out fp32 [b][o][pix].
// ---------------------------------------------------------------------------
__global__ __launch_bounds__(256) void k_out_mfma(
    const u16* __restrict__ AOF, const u16* __restrict__ WO,
    const float* __restrict__ bout, const float* __restrict__ gate,
    float* __restrict__ out) {
  const int ob = blockIdx.x, pb = blockIdx.y, b = blockIdx.z;
  const int wv = threadIdx.x >> 6, lane = threadIdx.x & 63;
  const int quad = lane >> 4, l15 = lane & 15;
  const int o0 = ob * 64 + wv * 16;
  const int pix0 = pb * 128;

  const u16* arow = WO + (size_t)(o0 + l15) * C;
  bf16x8 af[8];
#pragma unroll
  for (int kc = 0; kc < 8; ++kc)
    af[kc] = *(const bf16x8*)(arow + kc * 32 + quad * 8);

  const u16* ab = AOF + (size_t)(b * 64 + pb * 8) * 8 * 512 + lane * 8;
  f32x4 acc[8];
#pragma unroll
  for (int nt = 0; nt < 8; ++nt) acc[nt] = (f32x4){0.f, 0.f, 0.f, 0.f};

  for (int kc = 0; kc < 8; ++kc) {
#pragma unroll
    for (int nt = 0; nt < 8; ++nt) {
      bf16x8 bfr = *(const bf16x8*)(ab + (size_t)(nt * 8 + kc) * 512);
      acc[nt] = __builtin_amdgcn_mfma_f32_16x16x32_bf16(af[kc], bfr, acc[nt], 0, 0, 0);
    }
  }

#pragma unroll
  for (int nt = 0; nt < 8; ++nt) {
    const int pix = pix0 + nt * 16 + l15;
    const float gf = 1.f + gate[(b * 32 + (pix >> 5)) * 16 + ((pix & 31) >> 1)];
#pragma unroll
    for (int r = 0; r < 4; ++r) {
      const int o = o0 + 4 * quad + r;
      out[((size_t)b * C + o) * NPIX + pix] = acc[nt][r] * gf + bout[o];
    }
  }
}

// ---------------------------------------------------------------------------
extern "C" void kernel_launch(void* const* d_in, const int* in_sizes, int n_in,
                              void* d_out, int out_size, void* d_ws, size_t ws_size,
                              hipStream_t stream) {
  const float* x    = (const float*)d_in[0];
  const float* wqkv = (const float*)d_in[1];
  const float* wout = (const float*)d_in[2];
  const float* bout = (const float*)d_in[3];
  const float* wg1  = (const float*)d_in[4];
  const float* bg1  = (const float*)d_in[5];
  const float* wg2  = (const float*)d_in[6];
  const float* bg2  = (const float*)d_in[7];
  float* out = (float*)d_out;

  const size_t SZ = (size_t)B * HEADS * NPIX * D;   // 2,097,152
  u16* XT = (u16*)d_ws;
  u16* WQ = XT + SZ;
  u16* WO = WQ + (size_t)OC * C;
  u16* Q  = WO + (size_t)C * C;
  u16* Kq = Q + SZ;
  u16* VT = Kq + SZ;
  float* DIAG = (float*)(VT + SZ);
  float* COL  = DIAG + 256;
  float* GATE = COL + 2048;
  u16* AOT = XT;   // alias: XT dead after k_qkv_mfma

  hipLaunchKernelGGL(k_prep_gate, dim3(1024), dim3(256), 0, stream,
                     x, wqkv, wout, wg1, bg1, wg2, bg2, WQ, WO, XT, GATE);
  hipLaunchKernelGGL(k_qkv_mfma, dim3(12, 8, B), dim3(256), 0, stream,
                     XT, WQ, Q, Kq, VT);
  hipLaunchKernelGGL(k_red, dim3(72), dim3(256), 0, stream,
                     Q, Kq, VT, DIAG, COL);
  hipLaunchKernelGGL(k_attn, dim3(8, 64), dim3(512), 0, stream,
                     Q, Kq, VT, DIAG, COL, AOT);
  hipLaunchKernelGGL(k_out_mfma, dim3(4, 8, B), dim3(256), 0, stream,
                     AOT, WO, bout, GATE, out);
}

// Round 11
// 144.812 us; speedup vs baseline: 1.2240x; 1.0206x over previous
//
#include <hip/hip_runtime.h>
#include <hip/hip_bf16.h>
#include <math.h>

#define B 8
#define C 256
#define HEADS 8
#define D 32
#define NPIX 1024
#define OC 768
#define SCALE 0.17677669529663687f   // 1/sqrt(32)
#define LOG2E 1.4426950408889634f

typedef unsigned int uint;
typedef unsigned short u16;
typedef __attribute__((ext_vector_type(8))) short bf16x8;
typedef __attribute__((ext_vector_type(4))) short bf16x4;
typedef __attribute__((ext_vector_type(4))) float f32x4;

static __device__ inline u16 f2bf(float f) {   // RNE f32->bf16
  uint u = __float_as_uint(f);
  return (u16)((u + 0x7fffu + ((u >> 16) & 1u)) >> 16);
}
static __device__ inline float bfval(u16 v) { return __uint_as_float((uint)v << 16); }
static __device__ inline float bf_lo(uint u) { return __uint_as_float(u << 16); }
static __device__ inline float bf_hi(uint u) { return __uint_as_float(u & 0xffff0000u); }

// packed f32x2 -> bf16x2 (lowers to v_cvt_pk_bf16_f32 on gfx950)
static __device__ inline uint pk2(float lo, float hi) {
  union { __hip_bfloat162 h; uint u; } cv;
  cv.h = __float22bfloat162_rn(float2{lo, hi});
  return cv.u;
}

// ---------------------------------------------------------------------------
// P0: fused prep + gate. Blocks [0,256): weights fp32->bf16.
// Blocks [256,768): transpose-convert x -> FRAGMENT-ORDER XTF:
//   XTF[((b*64 + p16)*8 + kc)*512 + (quad*16 + l15)*8 + mm]
//     = x_bf16[pix = p16*16 + l15][c = kc*32 + quad*8 + mm]
// Blocks [768,1024): gate MLP (depends only on x) — overlaps with prep.
// ---------------------------------------------------------------------------
__global__ __launch_bounds__(256) void k_prep_gate(
    const float* __restrict__ x, const float* __restrict__ wqkv,
    const float* __restrict__ wout,
    const float* __restrict__ wg1, const float* __restrict__ bg1,
    const float* __restrict__ wg2, const float* __restrict__ bg2,
    u16* __restrict__ WQ, u16* __restrict__ WO, u16* __restrict__ XT,
    float* __restrict__ gate) {
  const int bid = blockIdx.x, t = threadIdx.x;
  __shared__ float smem[16 * 257 + 16 * 65];   // 20.6 KB, union across roles
  if (bid < 256) {
    const float* src;
    u16* dst;
    int base;
    if (bid < 192) { src = wqkv; dst = WQ; base = bid * 1024; }
    else           { src = wout; dst = WO; base = (bid - 192) * 1024; }
    float4 v = *(const float4*)(src + base + t * 4);
    uint2 pk = make_uint2((uint)f2bf(v.x) | ((uint)f2bf(v.y) << 16),
                          (uint)f2bf(v.z) | ((uint)f2bf(v.w) << 16));
    *(uint2*)(dst + base + t * 4) = pk;
    return;
  }
  if (bid < 768) {
    u16 (*tile)[65] = (u16(*)[65])smem;
    const int id = bid - 256;
    const int pt = id & 15, ct = (id >> 4) & 3, b = id >> 6;
    {
      const int px = t & 63, cq = t >> 6;
      const float* xb = x + ((size_t)(b * C + ct * 64)) * NPIX + pt * 64;
#pragma unroll
      for (int m = 0; m < 16; ++m) {
        const int c = cq * 16 + m;
        tile[c][px] = f2bf(xb[(size_t)c * NPIX + px]);
      }
    }
    __syncthreads();
    {
      const int cc = t & 63, pq = t >> 6;
      const int c = ct * 64 + cc;
      const int kc = c >> 5, quad = (c >> 3) & 3, mm = c & 7;
      u16* dst = XT + ((size_t)((b * 64 + pt * 4 + pq) * 8 + kc) * 512 +
                       quad * 128 + mm);
#pragma unroll
      for (int m = 0; m < 16; ++m)
        dst[m * 8] = tile[cc][pq * 16 + m];
    }
    return;
  }
  // ---- gate role ----
  const int id = bid - 768;
  const int h = id & 31, b = id >> 5;
  float* pl = smem;                // [16][257]
  float* gl = smem + 16 * 257;     // [16][65]
  {
    const int c = t;
    const float* row = x + ((size_t)(b * C + c) * NPIX + h * 32);
    float v[32];
#pragma unroll
    for (int m = 0; m < 32; ++m) v[m] = row[m];
#pragma unroll
    for (int k = 0; k < 16; ++k) pl[k * 257 + c] = fabsf(v[k] - v[31 - k]);
  }
  __syncthreads();

  const int o16 = t >> 4, k = t & 15;
#pragma unroll 1
  for (int p = 0; p < 4; ++p) {
    const int o = p * 16 + o16;
    const float* wr = wg1 + o * C;
    float a0 = 0.f, a1 = 0.f, a2 = 0.f, a3 = 0.f;
#pragma unroll 4
    for (int c = 0; c < C; c += 4) {
      a0 += wr[c]     * pl[k * 257 + c];
      a1 += wr[c + 1] * pl[k * 257 + c + 1];
      a2 += wr[c + 2] * pl[k * 257 + c + 2];
      a3 += wr[c + 3] * pl[k * 257 + c + 3];
    }
    float a = bg1[o] + ((a0 + a1) + (a2 + a3));
    gl[k * 65 + o] = 0.5f * a * (1.f + erff(a * 0.70710678118654752f));
  }
  __syncthreads();

  if (t < 16) {
    float s = bg2[0];
    for (int o = 0; o < 64; ++o)
      s += wg2[o] * gl[t * 65 + o];
    gate[(b * 32 + h) * 16 + t] = 1.f / (1.f + expf(-s));
  }
}

// ---------------------------------------------------------------------------
// K1: QKV GEMM via MFMA. The 64KB of XTF B-fragments a block consumes are
// IDENTICAL across its 4 waves -> stage per-kc 8KB slices into
// double-buffered LDS (T14 split: load early, write after compute).
// Each thread stages 32B/step; fragment reads are contiguous-per-lane
// ds_read_b128 (conflict-free). Cuts L2 fragment traffic 4x.
// Q pre-scaled by SCALE*LOG2E (k_red diag compensates). K/V stored in
// FRAGMENT-ORDER layouts (contiguous 4KB per 64-j tile):
//   KF[bh][ (j>>4)*512 + ((d>>3)*16 + (j&15))*8 + (d&7) ]         = K[j][d]
//   VF[bh][ ((j>>4)*2 + (d>>4))*256 + (((j>>2)&3)*16 + (d&15))*4 + (j&3) ]
// ---------------------------------------------------------------------------
__global__ __launch_bounds__(256) void k_qkv_mfma(
    const u16* __restrict__ XTF, const u16* __restrict__ WQ,
    u16* __restrict__ Q, u16* __restrict__ Kk, u16* __restrict__ VT) {
  const int ob = blockIdx.x, pb = blockIdx.y, b = blockIdx.z;
  const int t = threadIdx.x;
  const int wv = t >> 6, lane = t & 63;
  const int quad = lane >> 4, l15 = lane & 15;
  const int part = ob >> 2;
  const int odl = (ob & 3) * 64 + wv * 16;
  const int hh = odl >> 5, d0 = odl & 31;
  const int bh = b * HEADS + hh;
  const int pix0 = pb * 128;

  __shared__ u16 sb[2][4096];          // 2 x 8KB kc-slices

  const u16* arow = WQ + (size_t)(ob * 64 + wv * 16 + l15) * C;
  bf16x8 af[8];
#pragma unroll
  for (int kc = 0; kc < 8; ++kc)
    af[kc] = *(const bf16x8*)(arow + kc * 32 + quad * 8);

  const u16* xb = XTF + (size_t)(b * 64 + pb * 8) * 8 * 512;
  const int snt = t >> 5, si = (t & 31) * 16;    // stage: chunk, u16 offset

  f32x4 acc[8];
#pragma unroll
  for (int nt = 0; nt < 8; ++nt) acc[nt] = (f32x4){0.f, 0.f, 0.f, 0.f};

  // prologue: stage kc=0 slice into buffer 0
  {
    const u16* p = xb + (size_t)(snt * 8 + 0) * 512 + si;
    uint4 r0 = *(const uint4*)(p);
    uint4 r1 = *(const uint4*)(p + 8);
    u16* d = &sb[0][snt * 512 + si];
    *(uint4*)(d) = r0;
    *(uint4*)(d + 8) = r1;
  }
  __syncthreads();

  int cur = 0;
  for (int kc = 0; kc < 8; ++kc) {
    uint4 r0, r1;
    if (kc < 7) {                      // issue next-slice loads early
      const u16* p = xb + (size_t)(snt * 8 + kc + 1) * 512 + si;
      r0 = *(const uint4*)(p);
      r1 = *(const uint4*)(p + 8);
    }
    const u16* s = &sb[cur][0];
#pragma unroll
    for (int nt = 0; nt < 8; ++nt) {
      bf16x8 bfr = *(const bf16x8*)(s + nt * 512 + lane * 8);
      acc[nt] = __builtin_amdgcn_mfma_f32_16x16x32_bf16(af[kc], bfr, acc[nt], 0, 0, 0);
    }
    if (kc < 7) {                      // write after compute (latency hidden)
      u16* d = &sb[cur ^ 1][snt * 512 + si];
      *(uint4*)(d) = r0;
      *(uint4*)(d + 8) = r1;
    }
    __syncthreads();
    cur ^= 1;
  }

  if (part == 0) {
    const float qs = SCALE * LOG2E;
    u16* dst = Q + (size_t)bh * NPIX * D;
#pragma unroll
    for (int nt = 0; nt < 8; ++nt) {
      const int pix = pix0 + nt * 16 + l15;
      uint2 pk = make_uint2(
          (uint)f2bf(acc[nt][0] * qs) | ((uint)f2bf(acc[nt][1] * qs) << 16),
          (uint)f2bf(acc[nt][2] * qs) | ((uint)f2bf(acc[nt][3] * qs) << 16));
      *(uint2*)(dst + (size_t)pix * D + d0 + 4 * quad) = pk;
    }
  } else if (part == 1) {
    // KF fragment-order: rows o = d0+4*quad+r, r=0..3 land in one uint2
    u16* kfb = Kk + (size_t)bh * NPIX * D;
    const int lane_k8 = (((d0 >> 3) + (quad >> 1)) * 16 + l15) * 8 + (quad & 1) * 4;
#pragma unroll
    for (int nt = 0; nt < 8; ++nt) {
      uint2 pk = make_uint2(
          (uint)f2bf(acc[nt][0]) | ((uint)f2bf(acc[nt][1]) << 16),
          (uint)f2bf(acc[nt][2]) | ((uint)f2bf(acc[nt][3]) << 16));
      *(uint2*)(kfb + (size_t)(pb * 8 + nt) * 512 + lane_k8) = pk;
    }
  } else {
    u16* vb = VT + (size_t)bh * NPIX * D;
#pragma unroll
    for (int nt = 0; nt < 8; ++nt) {
      const int pix = pix0 + nt * 16 + l15;           // j
      const int jb16 = pix >> 4, qa = (pix >> 2) & 3, m = pix & 3;
#pragma unroll
      for (int r = 0; r < 4; ++r) {
        const int d = d0 + 4 * quad + r;              // 0..31
        const int nta = d >> 4, l15a = d & 15;
        vb[((size_t)(jb16 * 2 + nta) * 64 + qa * 16 + l15a) * 4 + m] =
            f2bf(acc[nt][r]);
      }
    }
  }
}

// ---------------------------------------------------------------------------
// R: fused reductions. Blocks [0,8): diag_vec[b] (Q carries SCALE*LOG2E, so
// final factor is 0.125/LOG2E; K read via KF layout). Blocks [8,72):
// colsum[bh] over the VF layout.
// ---------------------------------------------------------------------------
__global__ __launch_bounds__(256) void k_red(
    const u16* __restrict__ Q, const u16* __restrict__ KF,
    const u16* __restrict__ VT, float* __restrict__ diagv,
    float* __restrict__ colsum) {
  const int bid = blockIdx.x, tid = threadIdx.x;
  __shared__ float red[256];
  if (bid < 8) {
    const int b = bid;
    const int hh = tid >> 5, dd = tid & 31;
    const u16* qb = Q + (size_t)(b * HEADS + hh) * NPIX * D;
    const u16* kb = KF + (size_t)(b * HEADS + hh) * NPIX * D;
    float s = 0.f;
#pragma unroll 4
    for (int t = 0; t < 32; ++t) {
      const int j = t * 33;
      float qv = bfval(qb[(size_t)j * D + dd]);
      float kv = bfval(kb[(size_t)(j >> 4) * 512 +
                          ((dd >> 3) * 16 + (j & 15)) * 8 + (dd & 7)]);
      s += qv * kv;
    }
    red[tid] = s;
    __syncthreads();
    if (tid < 32) {
      float v = 0.f;
#pragma unroll
      for (int h8 = 0; h8 < 8; ++h8) v += red[h8 * 32 + tid];
      diagv[b * 32 + tid] = v * (0.125f / LOG2E);
    }
  } else {
    const int bh = bid - 8;
    const int d = tid >> 3, sl = tid & 7;
    const int nta = d >> 4, l15a = d & 15;
    const u16* vb = VT + (size_t)bh * NPIX * D;
    float s = 0.f;
    for (int jb = 0; jb < 8; ++jb) {
      const int jb16 = sl * 8 + jb;
#pragma unroll
      for (int qa = 0; qa < 4; ++qa) {
        const uint2 u = *(const uint2*)(
            vb + ((size_t)(jb16 * 2 + nta) * 64 + qa * 16 + l15a) * 4);
        s += bf_lo(u.x) + bf_hi(u.x) + bf_lo(u.y) + bf_hi(u.y);
      }
    }
    red[tid] = s;
    __syncthreads();
    if (tid < 32) {
      float v = 0.f;
#pragma unroll
      for (int g = 0; g < 8; ++g) v += red[tid * 8 + g];
      colsum[bh * D + tid] = v;
    }
  }
}

// ---------------------------------------------------------------------------
// K2: MFMA flash attention, 8-wave blocks sharing double-buffered LDS K/V,
// T14 async-stage split: global load issued at iteration top, LDS write
// deferred to after compute so HBM/L2 latency hides under S+exp+PV.
// Grid (8 qchunks of 128, 64 bh), 512 thr. Epilogue stores FRAGMENT-ORDER
// AOF (XTF-style) so k_out's B-fragment loads are contiguous 1KB bursts.
// ---------------------------------------------------------------------------
__global__ __launch_bounds__(512, 4) void k_attn(
    const u16* __restrict__ Q, const u16* __restrict__ KF,
    const u16* __restrict__ VF, const float* __restrict__ diagv,
    const float* __restrict__ colsum, u16* __restrict__ AOT) {
  const int qc = blockIdx.x;           // 0..7
  const int bh = blockIdx.y;           // 0..63
  const int b = bh >> 3, hh = bh & 7;
  const int wv = threadIdx.x >> 6, lane = threadIdx.x & 63;
  const int quad = lane >> 4, l15 = lane & 15;
  const int i0 = qc * 128 + wv * 16;

  __shared__ u16 sbuf[2][4096];        // 2 x 8KB: [K 4KB | V 4KB]

  const u16* Qb  = Q  + (size_t)bh * NPIX * D;
  const u16* KFb = KF + (size_t)bh * NPIX * D;
  const u16* VFb = VF + (size_t)bh * NPIX * D;

  bf16x8 qfrag = *(const bf16x8*)(Qb + (size_t)(i0 + l15) * D + quad * 8);

  f32x4 oacc[2];
  oacc[0] = (f32x4){0.f, 0.f, 0.f, 0.f};
  oacc[1] = (f32x4){0.f, 0.f, 0.f, 0.f};
  float lacc[4] = {};

  // staging role: waves 0-3 copy the K tile quarters, waves 4-7 the V tile
  const int soff = (wv >= 4 ? 2048 : 0) + (wv & 3) * 512 + lane * 8;
  const u16* gsrc = (wv < 4 ? KFb : VFb) + (wv & 3) * 512 + lane * 8;
  u16* ldst0 = &sbuf[0][soff];
  u16* ldst1 = &sbuf[1][soff];

  // prologue: stage tile 0 into buffer 0
  *(uint4*)(ldst0) = *(const uint4*)(gsrc);
  __syncthreads();

  int cur = 0;
  for (int it = 0; it < 16; ++it) {
    uint4 pre;
    if (it < 15)                       // issue next-tile load EARLY
      pre = *(const uint4*)(gsrc + (size_t)(it + 1) * 2048);
    const u16* sK = cur ? &sbuf[1][0] : &sbuf[0][0];
    const u16* sV = sK + 2048;

    // S^T = K Q^T: lane holds P^T rows j = jt*16+quad*4+r, col i = l15
    f32x4 st[4];
#pragma unroll
    for (int jt = 0; jt < 4; ++jt) {
      bf16x8 kfrag = *(const bf16x8*)(sK + jt * 512 + lane * 8);
      st[jt] = __builtin_amdgcn_mfma_f32_16x16x32_bf16(
          kfrag, qfrag, (f32x4){0.f, 0.f, 0.f, 0.f}, 0, 0, 0);
    }

    // exp (arg pre-scaled by SCALE*LOG2E at QKV time) + row-sum accumulate
#pragma unroll
    for (int jt = 0; jt < 4; ++jt)
#pragma unroll
      for (int r = 0; r < 4; ++r) {
        float pv = exp2f(fminf(st[jt][r], 80.f));
        lacc[r] += pv;
        st[jt][r] = pv;
      }

    // pack P in-register (A-frag of K=16 MFMA) + PV, no cross-lane movement
    __builtin_amdgcn_s_setprio(1);
#pragma unroll
    for (int jt = 0; jt < 4; ++jt) {
      union { uint u[2]; bf16x4 v; } pa;
      pa.u[0] = pk2(st[jt][0], st[jt][1]);
      pa.u[1] = pk2(st[jt][2], st[jt][3]);
#pragma unroll
      for (int nt = 0; nt < 2; ++nt) {
        bf16x4 vfr = *(const bf16x4*)(sV + (jt * 2 + nt) * 256 + lane * 4);
        oacc[nt] = __builtin_amdgcn_mfma_f32_16x16x16bf16_1k(
            pa.v, vfr, oacc[nt], 0, 0, 0);
      }
    }
    __builtin_amdgcn_s_setprio(0);

    if (it < 15)                       // write LATE (latency already hidden)
      *(uint4*)(cur ? ldst0 : ldst1) = pre;
    __syncthreads();   // staged writes visible; all waves done with cur
    cur ^= 1;
  }

  // row-sum: lane already has 16 j-classes for its row; reduce across quads
  float lt = (lacc[0] + lacc[1]) + (lacc[2] + lacc[3]);
  lt += __shfl_xor(lt, 16, 64);
  lt += __shfl_xor(lt, 32, 64);
  const float linv = 1.f / lt;
  // oacc rows are i = quad*4+r; fetch 1/l from lane l15 = quad*4+r
  float rinv[4];
#pragma unroll
  for (int r = 0; r < 4; ++r) rinv[r] = __shfl(linv, quad * 4 + r, 64);

  // epilogue: normalize, diag term (rows < 32), store AOF fragment-order
  const bool do_diag = (i0 < 32);
  const int p16 = i0 >> 4;
  u16* aobase = AOT + ((size_t)(b * 64 + p16) * 8 + hh) * 512 + (l15 & 7);
  const int hi8 = l15 >> 3;
#pragma unroll
  for (int nt = 0; nt < 2; ++nt) {
    const int qa = nt * 2 + hi8;     // ch = hh*32 + qa*8 + (l15&7) = hh*32+nt*16+l15
    float cs = do_diag ? colsum[bh * D + (nt * 16 + l15)] : 0.f;
#pragma unroll
    for (int r = 0; r < 4; ++r) {
      const int irow = i0 + quad * 4 + r;
      float o = oacc[nt][r] * rinv[r];
      if (do_diag) o += 0.3f * diagv[b * 32 + irow] * cs;
      aobase[(qa * 16 + quad * 4 + r) * 8] = f2bf(o);
    }
  }
}

// ---------------------------------------------------------------------------
// K4: output GEMM via MFMA, AOF fragment-order B loads (1KB bursts),
// gate+bias fused. out fp32 [b][o][pix].
// ---------------------------------------------------------------------------
__global__ __launch_bounds__(256) void k_out_mfma(
    const u16* __restrict__ AOF, const u16* __restrict__ WO,
    const float* __restrict__ bout, const float* __restrict__ gate,
    float* __restrict__ out) {
  const int ob = blockIdx.x, pb = blockIdx.y, b = blockIdx.z;
  const int wv = threadIdx.x >> 6, lane = threadIdx.x & 63;
  const int quad = lane >> 4, l15 = lane & 15;
  const int o0 = ob * 64 + wv * 16;
  const int pix0 = pb * 128;

  const u16* arow = WO + (size_t)(o0 + l15) * C;
  bf16x8 af[8];
#pragma unroll
  for (int kc = 0; kc < 8; ++kc)
    af[kc] = *(const bf16x8*)(arow + kc * 32 + quad * 8);

  const u16* ab = AOF + (size_t)(b * 64 + pb * 8) * 8 * 512 + lane * 8;
  f32x4 acc[8];
#pragma unroll
  for (int nt = 0; nt < 8; ++nt) acc[nt] = (f32x4){0.f, 0.f, 0.f, 0.f};

  for (int kc = 0; kc < 8; ++kc) {
#pragma unroll
    for (int nt = 0; nt < 8; ++nt) {
      bf16x8 bfr = *(const bf16x8*)(ab + (size_t)(nt * 8 + kc) * 512);
      acc[nt] = __builtin_amdgcn_mfma_f32_16x16x32_bf16(af[kc], bfr, acc[nt], 0, 0, 0);
    }
  }

#pragma unroll
  for (int nt = 0; nt < 8; ++nt) {
    const int pix = pix0 + nt * 16 + l15;
    const float gf = 1.f + gate[(b * 32 + (pix >> 5)) * 16 + ((pix & 31) >> 1)];
#pragma unroll
    for (int r = 0; r < 4; ++r) {
      const int o = o0 + 4 * quad + r;
      out[((size_t)b * C + o) * NPIX + pix] = acc[nt][r] * gf + bout[o];
    }
  }
}

// ---------------------------------------------------------------------------
extern "C" void kernel_launch(void* const* d_in, const int* in_sizes, int n_in,
                              void* d_out, int out_size, void* d_ws, size_t ws_size,
                              hipStream_t stream) {
  const float* x    = (const float*)d_in[0];
  const float* wqkv = (const float*)d_in[1];
  const float* wout = (const float*)d_in[2];
  const float* bout = (const float*)d_in[3];
  const float* wg1  = (const float*)d_in[4];
  const float* bg1  = (const float*)d_in[5];
  const float* wg2  = (const float*)d_in[6];
  const float* bg2  = (const float*)d_in[7];
  float* out = (float*)d_out;

  const size_t SZ = (size_t)B * HEADS * NPIX * D;   // 2,097,152
  u16* XT = (u16*)d_ws;
  u16* WQ = XT + SZ;
  u16* WO = WQ + (size_t)OC * C;
  u16* Q  = WO + (size_t)C * C;
  u16* Kq = Q + SZ;
  u16* VT = Kq + SZ;
  float* DIAG = (float*)(VT + SZ);
  float* COL  = DIAG + 256;
  float* GATE = COL + 2048;
  u16* AOT = XT;   // alias: XT dead after k_qkv_mfma

  hipLaunchKernelGGL(k_prep_gate, dim3(1024), dim3(256), 0, stream,
                     x, wqkv, wout, wg1, bg1, wg2, bg2, WQ, WO, XT, GATE);
  hipLaunchKernelGGL(k_qkv_mfma, dim3(12, 8, B), dim3(256), 0, stream,
                     XT, WQ, Q, Kq, VT);
  hipLaunchKernelGGL(k_red, dim3(72), dim3(256), 0, stream,
                     Q, Kq, VT, DIAG, COL);
  hipLaunchKernelGGL(k_attn, dim3(8, 64), dim3(512), 0, stream,
                     Q, Kq, VT, DIAG, COL, AOT);
  hipLaunchKernelGGL(k_out_mfma, dim3(4, 8, B), dim3(256), 0, stream,
                     AOT, WO, bout, GATE, out);
}

// Round 12
// 144.770 us; speedup vs baseline: 1.2244x; 1.0003x over previous
//
#include <hip/hip_runtime.h>
#include <hip/hip_bf16.h>
#include <math.h>

#define B 8
#define C 256
#define HEADS 8
#define D 32
#define NPIX 1024
#define OC 768
#define SCALE 0.17677669529663687f   // 1/sqrt(32)
#define LOG2E 1.4426950408889634f

typedef unsigned int uint;
typedef unsigned short u16;
typedef __attribute__((ext_vector_type(8))) short bf16x8;
typedef __attribute__((ext_vector_type(4))) short bf16x4;
typedef __attribute__((ext_vector_type(4))) float f32x4;

static __device__ inline u16 f2bf(float f) {   // RNE f32->bf16
  uint u = __float_as_uint(f);
  return (u16)((u + 0x7fffu + ((u >> 16) & 1u)) >> 16);
}
static __device__ inline float bfval(u16 v) { return __uint_as_float((uint)v << 16); }
static __device__ inline float bf_lo(uint u) { return __uint_as_float(u << 16); }
static __device__ inline float bf_hi(uint u) { return __uint_as_float(u & 0xffff0000u); }

// packed f32x2 -> bf16x2 (lowers to v_cvt_pk_bf16_f32 on gfx950)
static __device__ inline uint pk2(float lo, float hi) {
  union { __hip_bfloat162 h; uint u; } cv;
  cv.h = __float22bfloat162_rn(float2{lo, hi});
  return cv.u;
}

// ---------------------------------------------------------------------------
// P0: fused prep + gate. Blocks [0,256): weights fp32->bf16.
// Blocks [256,768): transpose-convert x -> FRAGMENT-ORDER XTF:
//   XTF[((b*64 + p16)*8 + kc)*512 + (quad*16 + l15)*8 + mm]
//     = x_bf16[pix = p16*16 + l15][c = kc*32 + quad*8 + mm]
// Blocks [768,1024): gate MLP (depends only on x) — overlaps with prep.
// ---------------------------------------------------------------------------
__global__ __launch_bounds__(256) void k_prep_gate(
    const float* __restrict__ x, const float* __restrict__ wqkv,
    const float* __restrict__ wout,
    const float* __restrict__ wg1, const float* __restrict__ bg1,
    const float* __restrict__ wg2, const float* __restrict__ bg2,
    u16* __restrict__ WQ, u16* __restrict__ WO, u16* __restrict__ XT,
    float* __restrict__ gate) {
  const int bid = blockIdx.x, t = threadIdx.x;
  __shared__ float smem[16 * 257 + 16 * 65];   // 20.6 KB, union across roles
  if (bid < 256) {
    const float* src;
    u16* dst;
    int base;
    if (bid < 192) { src = wqkv; dst = WQ; base = bid * 1024; }
    else           { src = wout; dst = WO; base = (bid - 192) * 1024; }
    float4 v = *(const float4*)(src + base + t * 4);
    uint2 pk = make_uint2((uint)f2bf(v.x) | ((uint)f2bf(v.y) << 16),
                          (uint)f2bf(v.z) | ((uint)f2bf(v.w) << 16));
    *(uint2*)(dst + base + t * 4) = pk;
    return;
  }
  if (bid < 768) {
    u16 (*tile)[65] = (u16(*)[65])smem;
    const int id = bid - 256;
    const int pt = id & 15, ct = (id >> 4) & 3, b = id >> 6;
    {
      const int px = t & 63, cq = t >> 6;
      const float* xb = x + ((size_t)(b * C + ct * 64)) * NPIX + pt * 64;
#pragma unroll
      for (int m = 0; m < 16; ++m) {
        const int c = cq * 16 + m;
        tile[c][px] = f2bf(xb[(size_t)c * NPIX + px]);
      }
    }
    __syncthreads();
    {
      const int cc = t & 63, pq = t >> 6;
      const int c = ct * 64 + cc;
      const int kc = c >> 5, quad = (c >> 3) & 3, mm = c & 7;
      u16* dst = XT + ((size_t)((b * 64 + pt * 4 + pq) * 8 + kc) * 512 +
                       quad * 128 + mm);
#pragma unroll
      for (int m = 0; m < 16; ++m)
        dst[m * 8] = tile[cc][pq * 16 + m];
    }
    return;
  }
  // ---- gate role ----
  const int id = bid - 768;
  const int h = id & 31, b = id >> 5;
  float* pl = smem;                // [16][257]
  float* gl = smem + 16 * 257;     // [16][65]
  {
    const int c = t;
    const float* row = x + ((size_t)(b * C + c) * NPIX + h * 32);
    float v[32];
#pragma unroll
    for (int m = 0; m < 32; ++m) v[m] = row[m];
#pragma unroll
    for (int k = 0; k < 16; ++k) pl[k * 257 + c] = fabsf(v[k] - v[31 - k]);
  }
  __syncthreads();

  const int o16 = t >> 4, k = t & 15;
#pragma unroll 1
  for (int p = 0; p < 4; ++p) {
    const int o = p * 16 + o16;
    const float* wr = wg1 + o * C;
    float a0 = 0.f, a1 = 0.f, a2 = 0.f, a3 = 0.f;
#pragma unroll 4
    for (int c = 0; c < C; c += 4) {
      a0 += wr[c]     * pl[k * 257 + c];
      a1 += wr[c + 1] * pl[k * 257 + c + 1];
      a2 += wr[c + 2] * pl[k * 257 + c + 2];
      a3 += wr[c + 3] * pl[k * 257 + c + 3];
    }
    float a = bg1[o] + ((a0 + a1) + (a2 + a3));
    gl[k * 65 + o] = 0.5f * a * (1.f + erff(a * 0.70710678118654752f));
  }
  __syncthreads();

  if (t < 16) {
    float s = bg2[0];
    for (int o = 0; o < 64; ++o)
      s += wg2[o] * gl[t * 65 + o];
    gate[(b * 32 + h) * 16 + t] = 1.f / (1.f + expf(-s));
  }
}

// ---------------------------------------------------------------------------
// K1: QKV GEMM via MFMA with block-shared double-buffered LDS staging of
// the XTF B-fragments (identical across the 4 waves; T14 load-early/
// write-late). Q pre-scaled by SCALE*LOG2E. K/V in FRAGMENT-ORDER:
//   KF[bh][ (j>>4)*512 + ((d>>3)*16 + (j&15))*8 + (d&7) ]         = K[j][d]
//   VF[bh][ ((j>>4)*2 + (d>>4))*256 + (((j>>2)&3)*16 + (d&15))*4 + (j&3) ]
// ---------------------------------------------------------------------------
__global__ __launch_bounds__(256) void k_qkv_mfma(
    const u16* __restrict__ XTF, const u16* __restrict__ WQ,
    u16* __restrict__ Q, u16* __restrict__ Kk, u16* __restrict__ VT) {
  const int ob = blockIdx.x, pb = blockIdx.y, b = blockIdx.z;
  const int t = threadIdx.x;
  const int wv = t >> 6, lane = t & 63;
  const int quad = lane >> 4, l15 = lane & 15;
  const int part = ob >> 2;
  const int odl = (ob & 3) * 64 + wv * 16;
  const int hh = odl >> 5, d0 = odl & 31;
  const int bh = b * HEADS + hh;
  const int pix0 = pb * 128;

  __shared__ u16 sb[2][4096];          // 2 x 8KB kc-slices

  const u16* arow = WQ + (size_t)(ob * 64 + wv * 16 + l15) * C;
  bf16x8 af[8];
#pragma unroll
  for (int kc = 0; kc < 8; ++kc)
    af[kc] = *(const bf16x8*)(arow + kc * 32 + quad * 8);

  const u16* xb = XTF + (size_t)(b * 64 + pb * 8) * 8 * 512;
  const int snt = t >> 5, si = (t & 31) * 16;    // stage: chunk, u16 offset

  f32x4 acc[8];
#pragma unroll
  for (int nt = 0; nt < 8; ++nt) acc[nt] = (f32x4){0.f, 0.f, 0.f, 0.f};

  // prologue: stage kc=0 slice into buffer 0
  {
    const u16* p = xb + (size_t)(snt * 8 + 0) * 512 + si;
    uint4 r0 = *(const uint4*)(p);
    uint4 r1 = *(const uint4*)(p + 8);
    u16* d = &sb[0][snt * 512 + si];
    *(uint4*)(d) = r0;
    *(uint4*)(d + 8) = r1;
  }
  __syncthreads();

  int cur = 0;
  for (int kc = 0; kc < 8; ++kc) {
    uint4 r0, r1;
    if (kc < 7) {                      // issue next-slice loads early
      const u16* p = xb + (size_t)(snt * 8 + kc + 1) * 512 + si;
      r0 = *(const uint4*)(p);
      r1 = *(const uint4*)(p + 8);
    }
    const u16* s = &sb[cur][0];
#pragma unroll
    for (int nt = 0; nt < 8; ++nt) {
      bf16x8 bfr = *(const bf16x8*)(s + nt * 512 + lane * 8);
      acc[nt] = __builtin_amdgcn_mfma_f32_16x16x32_bf16(af[kc], bfr, acc[nt], 0, 0, 0);
    }
    if (kc < 7) {                      // write after compute (latency hidden)
      u16* d = &sb[cur ^ 1][snt * 512 + si];
      *(uint4*)(d) = r0;
      *(uint4*)(d + 8) = r1;
    }
    __syncthreads();
    cur ^= 1;
  }

  if (part == 0) {
    const float qs = SCALE * LOG2E;
    u16* dst = Q + (size_t)bh * NPIX * D;
#pragma unroll
    for (int nt = 0; nt < 8; ++nt) {
      const int pix = pix0 + nt * 16 + l15;
      uint2 pk = make_uint2(
          (uint)f2bf(acc[nt][0] * qs) | ((uint)f2bf(acc[nt][1] * qs) << 16),
          (uint)f2bf(acc[nt][2] * qs) | ((uint)f2bf(acc[nt][3] * qs) << 16));
      *(uint2*)(dst + (size_t)pix * D + d0 + 4 * quad) = pk;
    }
  } else if (part == 1) {
    // KF fragment-order: rows o = d0+4*quad+r, r=0..3 land in one uint2
    u16* kfb = Kk + (size_t)bh * NPIX * D;
    const int lane_k8 = (((d0 >> 3) + (quad >> 1)) * 16 + l15) * 8 + (quad & 1) * 4;
#pragma unroll
    for (int nt = 0; nt < 8; ++nt) {
      uint2 pk = make_uint2(
          (uint)f2bf(acc[nt][0]) | ((uint)f2bf(acc[nt][1]) << 16),
          (uint)f2bf(acc[nt][2]) | ((uint)f2bf(acc[nt][3]) << 16));
      *(uint2*)(kfb + (size_t)(pb * 8 + nt) * 512 + lane_k8) = pk;
    }
  } else {
    u16* vb = VT + (size_t)bh * NPIX * D;
#pragma unroll
    for (int nt = 0; nt < 8; ++nt) {
      const int pix = pix0 + nt * 16 + l15;           // j
      const int jb16 = pix >> 4, qa = (pix >> 2) & 3, m = pix & 3;
#pragma unroll
      for (int r = 0; r < 4; ++r) {
        const int d = d0 + 4 * quad + r;              // 0..31
        const int nta = d >> 4, l15a = d & 15;
        vb[((size_t)(jb16 * 2 + nta) * 64 + qa * 16 + l15a) * 4 + m] =
            f2bf(acc[nt][r]);
      }
    }
  }
}

// ---------------------------------------------------------------------------
// R: fused reductions. Blocks [0,8): diag_vec[b] (Q carries SCALE*LOG2E, so
// final factor is 0.125/LOG2E; K read via KF layout). Blocks [8,72):
// colsum[bh] over the VF layout.
// ---------------------------------------------------------------------------
__global__ __launch_bounds__(256) void k_red(
    const u16* __restrict__ Q, const u16* __restrict__ KF,
    const u16* __restrict__ VT, float* __restrict__ diagv,
    float* __restrict__ colsum) {
  const int bid = blockIdx.x, tid = threadIdx.x;
  __shared__ float red[256];
  if (bid < 8) {
    const int b = bid;
    const int hh = tid >> 5, dd = tid & 31;
    const u16* qb = Q + (size_t)(b * HEADS + hh) * NPIX * D;
    const u16* kb = KF + (size_t)(b * HEADS + hh) * NPIX * D;
    float s = 0.f;
#pragma unroll 4
    for (int t = 0; t < 32; ++t) {
      const int j = t * 33;
      float qv = bfval(qb[(size_t)j * D + dd]);
      float kv = bfval(kb[(size_t)(j >> 4) * 512 +
                          ((dd >> 3) * 16 + (j & 15)) * 8 + (dd & 7)]);
      s += qv * kv;
    }
    red[tid] = s;
    __syncthreads();
    if (tid < 32) {
      float v = 0.f;
#pragma unroll
      for (int h8 = 0; h8 < 8; ++h8) v += red[h8 * 32 + tid];
      diagv[b * 32 + tid] = v * (0.125f / LOG2E);
    }
  } else {
    const int bh = bid - 8;
    const int d = tid >> 3, sl = tid & 7;
    const int nta = d >> 4, l15a = d & 15;
    const u16* vb = VT + (size_t)bh * NPIX * D;
    float s = 0.f;
    for (int jb = 0; jb < 8; ++jb) {
      const int jb16 = sl * 8 + jb;
#pragma unroll
      for (int qa = 0; qa < 4; ++qa) {
        const uint2 u = *(const uint2*)(
            vb + ((size_t)(jb16 * 2 + nta) * 64 + qa * 16 + l15a) * 4);
        s += bf_lo(u.x) + bf_hi(u.x) + bf_lo(u.y) + bf_hi(u.y);
      }
    }
    red[tid] = s;
    __syncthreads();
    if (tid < 32) {
      float v = 0.f;
#pragma unroll
      for (int g = 0; g < 8; ++g) v += red[tid * 8 + g];
      colsum[bh * D + tid] = v;
    }
  }
}

// ---------------------------------------------------------------------------
// K2: MFMA flash attention, 8-wave blocks, KVBLK=128: stage TWO 64-j tiles
// per step (32KB double-buffered LDS) -> 8 barriers instead of 16, 2x
// compute per barrier interval. T14 load-early/write-late staging.
// Grid (8 qchunks of 128, 64 bh), 512 thr. Epilogue stores FRAGMENT-ORDER
// AOF (XTF-style) so k_out's B-fragment loads are contiguous 1KB bursts.
// ---------------------------------------------------------------------------
__global__ __launch_bounds__(512, 4) void k_attn(
    const u16* __restrict__ Q, const u16* __restrict__ KF,
    const u16* __restrict__ VF, const float* __restrict__ diagv,
    const float* __restrict__ colsum, u16* __restrict__ AOT) {
  const int qc = blockIdx.x;           // 0..7
  const int bh = blockIdx.y;           // 0..63
  const int b = bh >> 3, hh = bh & 7;
  const int wv = threadIdx.x >> 6, lane = threadIdx.x & 63;
  const int quad = lane >> 4, l15 = lane & 15;
  const int i0 = qc * 128 + wv * 16;

  __shared__ u16 sbuf[2][8192];        // 2 x 16KB: [K pair 8KB | V pair 8KB]

  const u16* Qb  = Q  + (size_t)bh * NPIX * D;
  const u16* KFb = KF + (size_t)bh * NPIX * D;
  const u16* VFb = VF + (size_t)bh * NPIX * D;

  bf16x8 qfrag = *(const bf16x8*)(Qb + (size_t)(i0 + l15) * D + quad * 8);

  f32x4 oacc[2];
  oacc[0] = (f32x4){0.f, 0.f, 0.f, 0.f};
  oacc[1] = (f32x4){0.f, 0.f, 0.f, 0.f};
  float lacc[4] = {};

  // staging role: waves 0-3 copy the K tile-pair, waves 4-7 the V tile-pair
  const int soff = (wv >= 4 ? 4096 : 0) + (wv & 3) * 1024 + lane * 16;
  const u16* gsrc = (wv < 4 ? KFb : VFb) + (wv & 3) * 1024 + lane * 16;

  // prologue: stage pair 0 into buffer 0
  {
    uint4 a0 = *(const uint4*)(gsrc);
    uint4 a1 = *(const uint4*)(gsrc + 8);
    *(uint4*)(&sbuf[0][soff]) = a0;
    *(uint4*)(&sbuf[0][soff + 8]) = a1;
  }
  __syncthreads();

  int cur = 0;
  for (int it = 0; it < 8; ++it) {
    uint4 p0, p1;
    if (it < 7) {                      // issue next-pair loads EARLY
      const u16* g = gsrc + (size_t)(it + 1) * 4096;
      p0 = *(const uint4*)(g);
      p1 = *(const uint4*)(g + 8);
    }
    const u16* base = cur ? &sbuf[1][0] : &sbuf[0][0];

#pragma unroll
    for (int h2 = 0; h2 < 2; ++h2) {
      const u16* sK = base + h2 * 2048;
      const u16* sV = base + 4096 + h2 * 2048;

      // S^T = K Q^T: lane holds P^T rows j = jt*16+quad*4+r, col i = l15
      f32x4 st[4];
#pragma unroll
      for (int jt = 0; jt < 4; ++jt) {
        bf16x8 kfrag = *(const bf16x8*)(sK + jt * 512 + lane * 8);
        st[jt] = __builtin_amdgcn_mfma_f32_16x16x32_bf16(
            kfrag, qfrag, (f32x4){0.f, 0.f, 0.f, 0.f}, 0, 0, 0);
      }

      // exp (arg pre-scaled by SCALE*LOG2E at QKV time) + row-sum accumulate
#pragma unroll
      for (int jt = 0; jt < 4; ++jt)
#pragma unroll
        for (int r = 0; r < 4; ++r) {
          float pv = exp2f(fminf(st[jt][r], 80.f));
          lacc[r] += pv;
          st[jt][r] = pv;
        }

      // pack P in-register (A-frag of K=16 MFMA) + PV, no cross-lane movement
      __builtin_amdgcn_s_setprio(1);
#pragma unroll
      for (int jt = 0; jt < 4; ++jt) {
        union { uint u[2]; bf16x4 v; } pa;
        pa.u[0] = pk2(st[jt][0], st[jt][1]);
        pa.u[1] = pk2(st[jt][2], st[jt][3]);
#pragma unroll
        for (int nt = 0; nt < 2; ++nt) {
          bf16x4 vfr = *(const bf16x4*)(sV + (jt * 2 + nt) * 256 + lane * 4);
          oacc[nt] = __builtin_amdgcn_mfma_f32_16x16x16bf16_1k(
              pa.v, vfr, oacc[nt], 0, 0, 0);
        }
      }
      __builtin_amdgcn_s_setprio(0);
    }

    if (it < 7) {                      // write LATE (latency already hidden)
      u16* d = cur ? &sbuf[0][soff] : &sbuf[1][soff];
      *(uint4*)(d) = p0;
      *(uint4*)(d + 8) = p1;
    }
    __syncthreads();   // staged writes visible; all waves done with cur
    cur ^= 1;
  }

  // row-sum: lane already has 16 j-classes for its row; reduce across quads
  float lt = (lacc[0] + lacc[1]) + (lacc[2] + lacc[3]);
  lt += __shfl_xor(lt, 16, 64);
  lt += __shfl_xor(lt, 32, 64);
  const float linv = 1.f / lt;
  // oacc rows are i = quad*4+r; fetch 1/l from lane l15 = quad*4+r
  float rinv[4];
#pragma unroll
  for (int r = 0; r < 4; ++r) rinv[r] = __shfl(linv, quad * 4 + r, 64);

  // epilogue: normalize, diag term (rows < 32), store AOF fragment-order
  const bool do_diag = (i0 < 32);
  const int p16 = i0 >> 4;
  u16* aobase = AOT + ((size_t)(b * 64 + p16) * 8 + hh) * 512 + (l15 & 7);
  const int hi8 = l15 >> 3;
#pragma unroll
  for (int nt = 0; nt < 2; ++nt) {
    const int qa = nt * 2 + hi8;     // ch = hh*32 + qa*8 + (l15&7) = hh*32+nt*16+l15
    float cs = do_diag ? colsum[bh * D + (nt * 16 + l15)] : 0.f;
#pragma unroll
    for (int r = 0; r < 4; ++r) {
      const int irow = i0 + quad * 4 + r;
      float o = oacc[nt][r] * rinv[r];
      if (do_diag) o += 0.3f * diagv[b * 32 + irow] * cs;
      aobase[(qa * 16 + quad * 4 + r) * 8] = f2bf(o);
    }
  }
}

// ---------------------------------------------------------------------------
// K4: output GEMM via MFMA, AOF B-fragments staged through block-shared
// double-buffered LDS (identical across 4 waves -> 4x L2 traffic cut;
// same proven pattern as k_qkv). Gate+bias fused. out fp32 [b][o][pix].
// ---------------------------------------------------------------------------
__global__ __launch_bounds__(256) void k_out_mfma(
    const u16* __restrict__ AOF, const u16* __restrict__ WO,
    const float* __restrict__ bout, const float* __restrict__ gate,
    float* __restrict__ out) {
  const int ob = blockIdx.x, pb = blockIdx.y, b = blockIdx.z;
  const int t = threadIdx.x;
  const int wv = t >> 6, lane = t & 63;
  const int quad = lane >> 4, l15 = lane & 15;
  const int o0 = ob * 64 + wv * 16;
  const int pix0 = pb * 128;

  __shared__ u16 sb[2][4096];          // 2 x 8KB kc-slices

  const u16* arow = WO + (size_t)(o0 + l15) * C;
  bf16x8 af[8];
#pragma unroll
  for (int kc = 0; kc < 8; ++kc)
    af[kc] = *(const bf16x8*)(arow + kc * 32 + quad * 8);

  const u16* ab = AOF + (size_t)(b * 64 + pb * 8) * 8 * 512;
  const int snt = t >> 5, si = (t & 31) * 16;    // stage: chunk, u16 offset

  f32x4 acc[8];
#pragma unroll
  for (int nt = 0; nt < 8; ++nt) acc[nt] = (f32x4){0.f, 0.f, 0.f, 0.f};

  // prologue: stage kc=0 slice into buffer 0
  {
    const u16* p = ab + (size_t)(snt * 8 + 0) * 512 + si;
    uint4 r0 = *(const uint4*)(p);
    uint4 r1 = *(const uint4*)(p + 8);
    u16* d = &sb[0][snt * 512 + si];
    *(uint4*)(d) = r0;
    *(uint4*)(d + 8) = r1;
  }
  __syncthreads();

  int cur = 0;
  for (int kc = 0; kc < 8; ++kc) {
    uint4 r0, r1;
    if (kc < 7) {                      // issue next-slice loads early
      const u16* p = ab + (size_t)(snt * 8 + kc + 1) * 512 + si;
      r0 = *(const uint4*)(p);
      r1 = *(const uint4*)(p + 8);
    }
    const u16* s = &sb[cur][0];
#pragma unroll
    for (int nt = 0; nt < 8; ++nt) {
      bf16x8 bfr = *(const bf16x8*)(s + nt * 512 + lane * 8);
      acc[nt] = __builtin_amdgcn_mfma_f32_16x16x32_bf16(af[kc], bfr, acc[nt], 0, 0, 0);
    }
    if (kc < 7) {                      // write after compute (latency hidden)
      u16* d = &sb[cur ^ 1][snt * 512 + si];
      *(uint4*)(d) = r0;
      *(uint4*)(d + 8) = r1;
    }
    __syncthreads();
    cur ^= 1;
  }

#pragma unroll
  for (int nt = 0; nt < 8; ++nt) {
    const int pix = pix0 + nt * 16 + l15;
    const float gf = 1.f + gate[(b * 32 + (pix >> 5)) * 16 + ((pix & 31) >> 1)];
#pragma unroll
    for (int r = 0; r < 4; ++r) {
      const int o = o0 + 4 * quad + r;
      out[((size_t)b * C + o) * NPIX + pix] = acc[nt][r] * gf + bout[o];
    }
  }
}

// ---------------------------------------------------------------------------
extern "C" void kernel_launch(void* const* d_in, const int* in_sizes, int n_in,
                              void* d_out, int out_size, void* d_ws, size_t ws_size,
                              hipStream_t stream) {
  const float* x    = (const float*)d_in[0];
  const float* wqkv = (const float*)d_in[1];
  const float* wout = (const float*)d_in[2];
  const float* bout = (const float*)d_in[3];
  const float* wg1  = (const float*)d_in[4];
  const float* bg1  = (const float*)d_in[5];
  const float* wg2  = (const float*)d_in[6];
  const float* bg2  = (const float*)d_in[7];
  float* out = (float*)d_out;

  const size_t SZ = (size_t)B * HEADS * NPIX * D;   // 2,097,152
  u16* XT = (u16*)d_ws;
  u16* WQ = XT + SZ;
  u16* WO = WQ + (size_t)OC * C;
  u16* Q  = WO + (size_t)C * C;
  u16* Kq = Q + SZ;
  u16* VT = Kq + SZ;
  float* DIAG = (float*)(VT + SZ);
  float* COL  = DIAG + 256;
  float* GATE = COL + 2048;
  u16* AOT = XT;   // alias: XT dead after k_qkv_mfma

  hipLaunchKernelGGL(k_prep_gate, dim3(1024), dim3(256), 0, stream,
                     x, wqkv, wout, wg1, bg1, wg2, bg2, WQ, WO, XT, GATE);
  hipLaunchKernelGGL(k_qkv_mfma, dim3(12, 8, B), dim3(256), 0, stream,
                     XT, WQ, Q, Kq, VT);
  hipLaunchKernelGGL(k_red, dim3(72), dim3(256), 0, stream,
                     Q, Kq, VT, DIAG, COL);
  hipLaunchKernelGGL(k_attn, dim3(8, 64), dim3(512), 0, stream,
                     Q, Kq, VT, DIAG, COL, AOT);
  hipLaunchKernelGGL(k_out_mfma, dim3(4, 8, B), dim3(256), 0, stream,
                     AOT, WO, bout, GATE, out);
}

// Round 13
// 144.068 us; speedup vs baseline: 1.2303x; 1.0049x over previous
//
#include <hip/hip_runtime.h>
#include <hip/hip_bf16.h>
#include <math.h>

#define B 8
#define C 256
#define HEADS 8
#define D 32
#define NPIX 1024
#define OC 768
#define SCALE 0.17677669529663687f   // 1/sqrt(32)
#define LOG2E 1.4426950408889634f

typedef unsigned int uint;
typedef unsigned short u16;
typedef __attribute__((ext_vector_type(8))) short bf16x8;
typedef __attribute__((ext_vector_type(4))) short bf16x4;
typedef __attribute__((ext_vector_type(4))) float f32x4;

static __device__ inline u16 f2bf(float f) {   // RNE f32->bf16
  uint u = __float_as_uint(f);
  return (u16)((u + 0x7fffu + ((u >> 16) & 1u)) >> 16);
}
static __device__ inline float bfval(u16 v) { return __uint_as_float((uint)v << 16); }
static __device__ inline float bf_lo(uint u) { return __uint_as_float(u << 16); }
static __device__ inline float bf_hi(uint u) { return __uint_as_float(u & 0xffff0000u); }

// packed f32x2 -> bf16x2 (lowers to v_cvt_pk_bf16_f32 on gfx950)
static __device__ inline uint pk2(float lo, float hi) {
  union { __hip_bfloat162 h; uint u; } cv;
  cv.h = __float22bfloat162_rn(float2{lo, hi});
  return cv.u;
}

// ---------------------------------------------------------------------------
// P0: fused prep + gate. Blocks [0,256): weights fp32->bf16 (block 0 also
// zeroes colsum for k_qkv's atomic accumulation).
// Blocks [256,768): transpose-convert x -> FRAGMENT-ORDER XTF with
// VECTORIZED 16B stores (2 per thread instead of 16 scalar u16 stores):
//   XTF[((b*64 + p16)*8 + kc)*512 + (quad*16 + l15)*8 + mm]
//     = x_bf16[pix = p16*16 + l15][c = kc*32 + quad*8 + mm]
// Blocks [768,1024): gate MLP (depends only on x) — overlaps with prep.
// ---------------------------------------------------------------------------
__global__ __launch_bounds__(256) void k_prep_gate(
    const float* __restrict__ x, const float* __restrict__ wqkv,
    const float* __restrict__ wout,
    const float* __restrict__ wg1, const float* __restrict__ bg1,
    const float* __restrict__ wg2, const float* __restrict__ bg2,
    u16* __restrict__ WQ, u16* __restrict__ WO, u16* __restrict__ XT,
    float* __restrict__ gate, float* __restrict__ colsum) {
  const int bid = blockIdx.x, t = threadIdx.x;
  __shared__ float smem[16 * 257 + 16 * 65];   // 20.6 KB, union across roles
  if (bid < 256) {
    const float* src;
    u16* dst;
    int base;
    if (bid < 192) { src = wqkv; dst = WQ; base = bid * 1024; }
    else           { src = wout; dst = WO; base = (bid - 192) * 1024; }
    float4 v = *(const float4*)(src + base + t * 4);
    uint2 pk = make_uint2((uint)f2bf(v.x) | ((uint)f2bf(v.y) << 16),
                          (uint)f2bf(v.z) | ((uint)f2bf(v.w) << 16));
    *(uint2*)(dst + base + t * 4) = pk;
    if (bid == 0) {                    // zero colsum (2048 floats)
      float4 z = {0.f, 0.f, 0.f, 0.f};
      *(float4*)(colsum + t * 8) = z;
      *(float4*)(colsum + t * 8 + 4) = z;
    }
    return;
  }
  if (bid < 768) {
    u16 (*tile)[65] = (u16(*)[65])smem;
    const int id = bid - 256;
    const int pt = id & 15, ct = (id >> 4) & 3, b = id >> 6;
    {
      const int px = t & 63, cq = t >> 6;
      const float* xb = x + ((size_t)(b * C + ct * 64)) * NPIX + pt * 64;
#pragma unroll
      for (int m = 0; m < 16; ++m) {
        const int c = cq * 16 + m;
        tile[c][px] = f2bf(xb[(size_t)c * NPIX + px]);
      }
    }
    __syncthreads();
    {
#pragma unroll
      for (int uu = 0; uu < 2; ++uu) {
        const int u = t + uu * 256;
        const int kc2 = u >> 8, quad = (u >> 6) & 3;
        const int pq = (u >> 4) & 3, m = u & 15;
        const int px = pq * 16 + m;
        union { uint4 w; u16 h[8]; } pk;
#pragma unroll
        for (int mm = 0; mm < 8; ++mm)
          pk.h[mm] = tile[kc2 * 32 + quad * 8 + mm][px];
        u16* dst = XT + ((size_t)((b * 64 + pt * 4 + pq) * 8 + ct * 2 + kc2) * 512 +
                         quad * 128 + m * 8);
        *(uint4*)dst = pk.w;
      }
    }
    return;
  }
  // ---- gate role ----
  const int id = bid - 768;
  const int h = id & 31, b = id >> 5;
  float* pl = smem;                // [16][257]
  float* gl = smem + 16 * 257;     // [16][65]
  {
    const int c = t;
    const float* row = x + ((size_t)(b * C + c) * NPIX + h * 32);
    float v[32];
#pragma unroll
    for (int m = 0; m < 32; ++m) v[m] = row[m];
#pragma unroll
    for (int k = 0; k < 16; ++k) pl[k * 257 + c] = fabsf(v[k] - v[31 - k]);
  }
  __syncthreads();

  const int o16 = t >> 4, k = t & 15;
#pragma unroll 1
  for (int p = 0; p < 4; ++p) {
    const int o = p * 16 + o16;
    const float* wr = wg1 + o * C;
    float a0 = 0.f, a1 = 0.f, a2 = 0.f, a3 = 0.f;
#pragma unroll 4
    for (int c = 0; c < C; c += 4) {
      a0 += wr[c]     * pl[k * 257 + c];
      a1 += wr[c + 1] * pl[k * 257 + c + 1];
      a2 += wr[c + 2] * pl[k * 257 + c + 2];
      a3 += wr[c + 3] * pl[k * 257 + c + 3];
    }
    float a = bg1[o] + ((a0 + a1) + (a2 + a3));
    gl[k * 65 + o] = 0.5f * a * (1.f + erff(a * 0.70710678118654752f));
  }
  __syncthreads();

  if (t < 16) {
    float s = bg2[0];
    for (int o = 0; o < 64; ++o)
      s += wg2[o] * gl[t * 65 + o];
    gate[(b * 32 + h) * 16 + t] = 1.f / (1.f + expf(-s));
  }
}

// ---------------------------------------------------------------------------
// K1: QKV GEMM via MFMA with block-shared double-buffered LDS staging of
// the XTF B-fragments (identical across the 4 waves; T14 load-early/
// write-late). Q pre-scaled by SCALE*LOG2E. K/V in FRAGMENT-ORDER:
//   KF[bh][ (j>>4)*512 + ((d>>3)*16 + (j&15))*8 + (d&7) ]         = K[j][d]
//   VF[bh][ ((j>>4)*2 + (d>>4))*256 + (((j>>2)&3)*16 + (d&15))*4 + (j&3) ]
// Part-2 epilogue additionally accumulates colsum[bh][d] via l15-shuffle
// reduction + atomicAdd (replaces 64 of k_red's 72 blocks).
// ---------------------------------------------------------------------------
__global__ __launch_bounds__(256) void k_qkv_mfma(
    const u16* __restrict__ XTF, const u16* __restrict__ WQ,
    u16* __restrict__ Q, u16* __restrict__ Kk, u16* __restrict__ VT,
    float* __restrict__ colsum) {
  const int ob = blockIdx.x, pb = blockIdx.y, b = blockIdx.z;
  const int t = threadIdx.x;
  const int wv = t >> 6, lane = t & 63;
  const int quad = lane >> 4, l15 = lane & 15;
  const int part = ob >> 2;
  const int odl = (ob & 3) * 64 + wv * 16;
  const int hh = odl >> 5, d0 = odl & 31;
  const int bh = b * HEADS + hh;
  const int pix0 = pb * 128;

  __shared__ u16 sb[2][4096];          // 2 x 8KB kc-slices

  const u16* arow = WQ + (size_t)(ob * 64 + wv * 16 + l15) * C;
  bf16x8 af[8];
#pragma unroll
  for (int kc = 0; kc < 8; ++kc)
    af[kc] = *(const bf16x8*)(arow + kc * 32 + quad * 8);

  const u16* xb = XTF + (size_t)(b * 64 + pb * 8) * 8 * 512;
  const int snt = t >> 5, si = (t & 31) * 16;    // stage: chunk, u16 offset

  f32x4 acc[8];
#pragma unroll
  for (int nt = 0; nt < 8; ++nt) acc[nt] = (f32x4){0.f, 0.f, 0.f, 0.f};

  // prologue: stage kc=0 slice into buffer 0
  {
    const u16* p = xb + (size_t)(snt * 8 + 0) * 512 + si;
    uint4 r0 = *(const uint4*)(p);
    uint4 r1 = *(const uint4*)(p + 8);
    u16* d = &sb[0][snt * 512 + si];
    *(uint4*)(d) = r0;
    *(uint4*)(d + 8) = r1;
  }
  __syncthreads();

  int cur = 0;
  for (int kc = 0; kc < 8; ++kc) {
    uint4 r0, r1;
    if (kc < 7) {                      // issue next-slice loads early
      const u16* p = xb + (size_t)(snt * 8 + kc + 1) * 512 + si;
      r0 = *(const uint4*)(p);
      r1 = *(const uint4*)(p + 8);
    }
    const u16* s = &sb[cur][0];
#pragma unroll
    for (int nt = 0; nt < 8; ++nt) {
      bf16x8 bfr = *(const bf16x8*)(s + nt * 512 + lane * 8);
      acc[nt] = __builtin_amdgcn_mfma_f32_16x16x32_bf16(af[kc], bfr, acc[nt], 0, 0, 0);
    }
    if (kc < 7) {                      // write after compute (latency hidden)
      u16* d = &sb[cur ^ 1][snt * 512 + si];
      *(uint4*)(d) = r0;
      *(uint4*)(d + 8) = r1;
    }
    __syncthreads();
    cur ^= 1;
  }

  if (part == 0) {
    const float qs = SCALE * LOG2E;
    u16* dst = Q + (size_t)bh * NPIX * D;
#pragma unroll
    for (int nt = 0; nt < 8; ++nt) {
      const int pix = pix0 + nt * 16 + l15;
      uint2 pk = make_uint2(
          (uint)f2bf(acc[nt][0] * qs) | ((uint)f2bf(acc[nt][1] * qs) << 16),
          (uint)f2bf(acc[nt][2] * qs) | ((uint)f2bf(acc[nt][3] * qs) << 16));
      *(uint2*)(dst + (size_t)pix * D + d0 + 4 * quad) = pk;
    }
  } else if (part == 1) {
    // KF fragment-order: rows o = d0+4*quad+r, r=0..3 land in one uint2
    u16* kfb = Kk + (size_t)bh * NPIX * D;
    const int lane_k8 = (((d0 >> 3) + (quad >> 1)) * 16 + l15) * 8 + (quad & 1) * 4;
#pragma unroll
    for (int nt = 0; nt < 8; ++nt) {
      uint2 pk = make_uint2(
          (uint)f2bf(acc[nt][0]) | ((uint)f2bf(acc[nt][1]) << 16),
          (uint)f2bf(acc[nt][2]) | ((uint)f2bf(acc[nt][3]) << 16));
      *(uint2*)(kfb + (size_t)(pb * 8 + nt) * 512 + lane_k8) = pk;
    }
  } else {
    u16* vb = VT + (size_t)bh * NPIX * D;
    float cs[4] = {};
#pragma unroll
    for (int nt = 0; nt < 8; ++nt) {
      const int pix = pix0 + nt * 16 + l15;           // j
      const int jb16 = pix >> 4, qa = (pix >> 2) & 3, m = pix & 3;
#pragma unroll
      for (int r = 0; r < 4; ++r) {
        const int d = d0 + 4 * quad + r;              // 0..31
        const int nta = d >> 4, l15a = d & 15;
        const u16 hv = f2bf(acc[nt][r]);
        vb[((size_t)(jb16 * 2 + nta) * 64 + qa * 16 + l15a) * 4 + m] = hv;
        cs[r] += bfval(hv);            // colsum over bf16-rounded V
      }
    }
    // reduce the 128-pix partial over the 16 l15 lanes of this quad group
#pragma unroll
    for (int r = 0; r < 4; ++r) {
      cs[r] += __shfl_xor(cs[r], 1, 16);
      cs[r] += __shfl_xor(cs[r], 2, 16);
      cs[r] += __shfl_xor(cs[r], 4, 16);
      cs[r] += __shfl_xor(cs[r], 8, 16);
    }
    if (l15 == 0) {
#pragma unroll
      for (int r = 0; r < 4; ++r)
        atomicAdd(&colsum[bh * D + d0 + 4 * quad + r], cs[r]);
    }
  }
}

// ---------------------------------------------------------------------------
// R: diag_vec[b] only (colsum moved into k_qkv). 8 blocks. Q carries
// SCALE*LOG2E, so final factor is 0.125/LOG2E; K read via KF layout.
// ---------------------------------------------------------------------------
__global__ __launch_bounds__(256) void k_red(
    const u16* __restrict__ Q, const u16* __restrict__ KF,
    float* __restrict__ diagv) {
  const int b = blockIdx.x, tid = threadIdx.x;
  __shared__ float red[256];
  const int hh = tid >> 5, dd = tid & 31;
  const u16* qb = Q + (size_t)(b * HEADS + hh) * NPIX * D;
  const u16* kb = KF + (size_t)(b * HEADS + hh) * NPIX * D;
  float s = 0.f;
#pragma unroll 4
  for (int t = 0; t < 32; ++t) {
    const int j = t * 33;
    float qv = bfval(qb[(size_t)j * D + dd]);
    float kv = bfval(kb[(size_t)(j >> 4) * 512 +
                        ((dd >> 3) * 16 + (j & 15)) * 8 + (dd & 7)]);
    s += qv * kv;
  }
  red[tid] = s;
  __syncthreads();
  if (tid < 32) {
    float v = 0.f;
#pragma unroll
    for (int h8 = 0; h8 < 8; ++h8) v += red[h8 * 32 + tid];
    diagv[b * 32 + tid] = v * (0.125f / LOG2E);
  }
}

// ---------------------------------------------------------------------------
// K2: MFMA flash attention, 8-wave blocks, KVBLK=128: stage TWO 64-j tiles
// per step (32KB double-buffered LDS) -> 8 barriers, 2x compute per
// interval. T14 load-early/write-late staging.
// Grid (8 qchunks of 128, 64 bh), 512 thr. Epilogue stores FRAGMENT-ORDER
// AOF (XTF-style) so k_out's B-fragment loads are contiguous 1KB bursts.
// ---------------------------------------------------------------------------
__global__ __launch_bounds__(512, 4) void k_attn(
    const u16* __restrict__ Q, const u16* __restrict__ KF,
    const u16* __restrict__ VF, const float* __restrict__ diagv,
    const float* __restrict__ colsum, u16* __restrict__ AOT) {
  const int qc = blockIdx.x;           // 0..7
  const int bh = blockIdx.y;           // 0..63
  const int b = bh >> 3, hh = bh & 7;
  const int wv = threadIdx.x >> 6, lane = threadIdx.x & 63;
  const int quad = lane >> 4, l15 = lane & 15;
  const int i0 = qc * 128 + wv * 16;

  __shared__ u16 sbuf[2][8192];        // 2 x 16KB: [K pair 8KB | V pair 8KB]

  const u16* Qb  = Q  + (size_t)bh * NPIX * D;
  const u16* KFb = KF + (size_t)bh * NPIX * D;
  const u16* VFb = VF + (size_t)bh * NPIX * D;

  bf16x8 qfrag = *(const bf16x8*)(Qb + (size_t)(i0 + l15) * D + quad * 8);

  f32x4 oacc[2];
  oacc[0] = (f32x4){0.f, 0.f, 0.f, 0.f};
  oacc[1] = (f32x4){0.f, 0.f, 0.f, 0.f};
  float lacc[4] = {};

  // staging role: waves 0-3 copy the K tile-pair, waves 4-7 the V tile-pair
  const int soff = (wv >= 4 ? 4096 : 0) + (wv & 3) * 1024 + lane * 16;
  const u16* gsrc = (wv < 4 ? KFb : VFb) + (wv & 3) * 1024 + lane * 16;

  // prologue: stage pair 0 into buffer 0
  {
    uint4 a0 = *(const uint4*)(gsrc);
    uint4 a1 = *(const uint4*)(gsrc + 8);
    *(uint4*)(&sbuf[0][soff]) = a0;
    *(uint4*)(&sbuf[0][soff + 8]) = a1;
  }
  __syncthreads();

  int cur = 0;
  for (int it = 0; it < 8; ++it) {
    uint4 p0, p1;
    if (it < 7) {                      // issue next-pair loads EARLY
      const u16* g = gsrc + (size_t)(it + 1) * 4096;
      p0 = *(const uint4*)(g);
      p1 = *(const uint4*)(g + 8);
    }
    const u16* base = cur ? &sbuf[1][0] : &sbuf[0][0];

#pragma unroll
    for (int h2 = 0; h2 < 2; ++h2) {
      const u16* sK = base + h2 * 2048;
      const u16* sV = base + 4096 + h2 * 2048;

      // S^T = K Q^T: lane holds P^T rows j = jt*16+quad*4+r, col i = l15
      f32x4 st[4];
#pragma unroll
      for (int jt = 0; jt < 4; ++jt) {
        bf16x8 kfrag = *(const bf16x8*)(sK + jt * 512 + lane * 8);
        st[jt] = __builtin_amdgcn_mfma_f32_16x16x32_bf16(
            kfrag, qfrag, (f32x4){0.f, 0.f, 0.f, 0.f}, 0, 0, 0);
      }

      // exp (arg pre-scaled by SCALE*LOG2E at QKV time) + row-sum accumulate
#pragma unroll
      for (int jt = 0; jt < 4; ++jt)
#pragma unroll
        for (int r = 0; r < 4; ++r) {
          float pv = exp2f(fminf(st[jt][r], 80.f));
          lacc[r] += pv;
          st[jt][r] = pv;
        }

      // pack P in-register (A-frag of K=16 MFMA) + PV, no cross-lane movement
      __builtin_amdgcn_s_setprio(1);
#pragma unroll
      for (int jt = 0; jt < 4; ++jt) {
        union { uint u[2]; bf16x4 v; } pa;
        pa.u[0] = pk2(st[jt][0], st[jt][1]);
        pa.u[1] = pk2(st[jt][2], st[jt][3]);
#pragma unroll
        for (int nt = 0; nt < 2; ++nt) {
          bf16x4 vfr = *(const bf16x4*)(sV + (jt * 2 + nt) * 256 + lane * 4);
          oacc[nt] = __builtin_amdgcn_mfma_f32_16x16x16bf16_1k(
              pa.v, vfr, oacc[nt], 0, 0, 0);
        }
      }
      __builtin_amdgcn_s_setprio(0);
    }

    if (it < 7) {                      // write LATE (latency already hidden)
      u16* d = cur ? &sbuf[0][soff] : &sbuf[1][soff];
      *(uint4*)(d) = p0;
      *(uint4*)(d + 8) = p1;
    }
    __syncthreads();   // staged writes visible; all waves done with cur
    cur ^= 1;
  }

  // row-sum: lane already has 16 j-classes for its row; reduce across quads
  float lt = (lacc[0] + lacc[1]) + (lacc[2] + lacc[3]);
  lt += __shfl_xor(lt, 16, 64);
  lt += __shfl_xor(lt, 32, 64);
  const float linv = 1.f / lt;
  // oacc rows are i = quad*4+r; fetch 1/l from lane l15 = quad*4+r
  float rinv[4];
#pragma unroll
  for (int r = 0; r < 4; ++r) rinv[r] = __shfl(linv, quad * 4 + r, 64);

  // epilogue: normalize, diag term (rows < 32), store AOF fragment-order
  const bool do_diag = (i0 < 32);
  const int p16 = i0 >> 4;
  u16* aobase = AOT + ((size_t)(b * 64 + p16) * 8 + hh) * 512 + (l15 & 7);
  const int hi8 = l15 >> 3;
#pragma unroll
  for (int nt = 0; nt < 2; ++nt) {
    const int qa = nt * 2 + hi8;     // ch = hh*32 + qa*8 + (l15&7) = hh*32+nt*16+l15
    float cs = do_diag ? colsum[bh * D + (nt * 16 + l15)] : 0.f;
#pragma unroll
    for (int r = 0; r < 4; ++r) {
      const int irow = i0 + quad * 4 + r;
      float o = oacc[nt][r] * rinv[r];
      if (do_diag) o += 0.3f * diagv[b * 32 + irow] * cs;
      aobase[(qa * 16 + quad * 4 + r) * 8] = f2bf(o);
    }
  }
}

// ---------------------------------------------------------------------------
// K4: output GEMM via MFMA, AOF B-fragments staged through block-shared
// double-buffered LDS (identical across 4 waves -> 4x L2 traffic cut).
// Gate+bias fused. out fp32 [b][o][pix].
// ---------------------------------------------------------------------------
__global__ __launch_bounds__(256) void k_out_mfma(
    const u16* __restrict__ AOF, const u16* __restrict__ WO,
    const float* __restrict__ bout, const float* __restrict__ gate,
    float* __restrict__ out) {
  const int ob = blockIdx.x, pb = blockIdx.y, b = blockIdx.z;
  const int t = threadIdx.x;
  const int wv = t >> 6, lane = t & 63;
  const int quad = lane >> 4, l15 = lane & 15;
  const int o0 = ob * 64 + wv * 16;
  const int pix0 = pb * 128;

  __shared__ u16 sb[2][4096];          // 2 x 8KB kc-slices

  const u16* arow = WO + (size_t)(o0 + l15) * C;
  bf16x8 af[8];
#pragma unroll
  for (int kc = 0; kc < 8; ++kc)
    af[kc] = *(const bf16x8*)(arow + kc * 32 + quad * 8);

  const u16* ab = AOF + (size_t)(b * 64 + pb * 8) * 8 * 512;
  const int snt = t >> 5, si = (t & 31) * 16;    // stage: chunk, u16 offset

  f32x4 acc[8];
#pragma unroll
  for (int nt = 0; nt < 8; ++nt) acc[nt] = (f32x4){0.f, 0.f, 0.f, 0.f};

  // prologue: stage kc=0 slice into buffer 0
  {
    const u16* p = ab + (size_t)(snt * 8 + 0) * 512 + si;
    uint4 r0 = *(const uint4*)(p);
    uint4 r1 = *(const uint4*)(p + 8);
    u16* d = &sb[0][snt * 512 + si];
    *(uint4*)(d) = r0;
    *(uint4*)(d + 8) = r1;
  }
  __syncthreads();

  int cur = 0;
  for (int kc = 0; kc < 8; ++kc) {
    uint4 r0, r1;
    if (kc < 7) {                      // issue next-slice loads early
      const u16* p = ab + (size_t)(snt * 8 + kc + 1) * 512 + si;
      r0 = *(const uint4*)(p);
      r1 = *(const uint4*)(p + 8);
    }
    const u16* s = &sb[cur][0];
#pragma unroll
    for (int nt = 0; nt < 8; ++nt) {
      bf16x8 bfr = *(const bf16x8*)(s + nt * 512 + lane * 8);
      acc[nt] = __builtin_amdgcn_mfma_f32_16x16x32_bf16(af[kc], bfr, acc[nt], 0, 0, 0);
    }
    if (kc < 7) {                      // write after compute (latency hidden)
      u16* d = &sb[cur ^ 1][snt * 512 + si];
      *(uint4*)(d) = r0;
      *(uint4*)(d + 8) = r1;
    }
    __syncthreads();
    cur ^= 1;
  }

#pragma unroll
  for (int nt = 0; nt < 8; ++nt) {
    const int pix = pix0 + nt * 16 + l15;
    const float gf = 1.f + gate[(b * 32 + (pix >> 5)) * 16 + ((pix & 31) >> 1)];
#pragma unroll
    for (int r = 0; r < 4; ++r) {
      const int o = o0 + 4 * quad + r;
      out[((size_t)b * C + o) * NPIX + pix] = acc[nt][r] * gf + bout[o];
    }
  }
}

// ---------------------------------------------------------------------------
extern "C" void kernel_launch(void* const* d_in, const int* in_sizes, int n_in,
                              void* d_out, int out_size, void* d_ws, size_t ws_size,
                              hipStream_t stream) {
  const float* x    = (const float*)d_in[0];
  const float* wqkv = (const float*)d_in[1];
  const float* wout = (const float*)d_in[2];
  const float* bout = (const float*)d_in[3];
  const float* wg1  = (const float*)d_in[4];
  const float* bg1  = (const float*)d_in[5];
  const float* wg2  = (const float*)d_in[6];
  const float* bg2  = (const float*)d_in[7];
  float* out = (float*)d_out;

  const size_t SZ = (size_t)B * HEADS * NPIX * D;   // 2,097,152
  u16* XT = (u16*)d_ws;
  u16* WQ = XT + SZ;
  u16* WO = WQ + (size_t)OC * C;
  u16* Q  = WO + (size_t)C * C;
  u16* Kq = Q + SZ;
  u16* VT = Kq + SZ;
  float* DIAG = (float*)(VT + SZ);
  float* COL  = DIAG + 256;
  float* GATE = COL + 2048;
  u16* AOT = XT;   // alias: XT dead after k_qkv_mfma

  hipLaunchKernelGGL(k_prep_gate, dim3(1024), dim3(256), 0, stream,
                     x, wqkv, wout, wg1, bg1, wg2, bg2, WQ, WO, XT, GATE, COL);
  hipLaunchKernelGGL(k_qkv_mfma, dim3(12, 8, B), dim3(256), 0, stream,
                     XT, WQ, Q, Kq, VT, COL);
  hipLaunchKernelGGL(k_red, dim3(8), dim3(256), 0, stream,
                     Q, Kq, DIAG);
  hipLaunchKernelGGL(k_attn, dim3(8, 64), dim3(512), 0, stream,
                     Q, Kq, VT, DIAG, COL, AOT);
  hipLaunchKernelGGL(k_out_mfma, dim3(4, 8, B), dim3(256), 0, stream,
                     AOT, WO, bout, GATE, out);
}